// Round 5
// baseline (2250.186 us; speedup 1.0000x reference)
//
#include <hip/hip_runtime.h>
#include <hip/hip_cooperative_groups.h>
#include <hip/hip_bf16.h>
#include <math.h>

namespace cg = cooperative_groups;

// ---------------- problem constants ----------------
#define BSZ   8
#define LSEQ  107
#define NNF   17
#define NEF   9
#define NH    128
#define EHD   32
#define H3D   32
#define NLAY  10
#define PCD   32
#define TLAY  3
#define THD   8
#define FFD   256
#define NCLS  3
#define DD    160          // NH + PC
#define HDD   20           // D / TH
#define NND   856          // nodes
#define NPAD  896          // padded to 14*64 for GEMM
#define NE    2896         // edges
#define NCOLS 4352         // 4096 (msg) + 128 (b2) + 128 (root)
#define NCT   68           // 4352 / 64 column tiles

typedef __bf16 bf16;
typedef __bf16 bf16x8 __attribute__((ext_vector_type(8)));
typedef float  f32x4  __attribute__((ext_vector_type(4)));

struct Params {
    const float *x, *eattr, *cheb_w, *cheb_b, *ee_w, *ee_b, *mlp_w1, *mlp_b1,
                *mlp_w2, *mlp_b2, *root_w, *conv_b, *ln_g, *ln_b,
                *ain_w, *ain_b, *aow, *aob, *ffw1, *ffb1, *ffw2, *ffb2,
                *t1g, *t1b, *t2g, *t2b, *lin_w, *lin_b;
    const int *ei;
    bf16 *bpack, *hbf, *HW;
    float *t1all, *hA, *hB, *tbuf, *qkv, *abuf, *f1, *out;
};

__device__ __forceinline__ float geluf(float z) {
    return 0.5f * z * (1.0f + erff(z * 0.70710678118654752f));
}
__device__ __forceinline__ float wred(float v) {
    #pragma unroll
    for (int o = 32; o; o >>= 1) v += __shfl_xor(v, o, 64);
    return v;
}
__device__ __forceinline__ float dinv_path(int n) {
    return (n == 0 || n == LSEQ - 1) ? 1.0f : 0.70710678118654752f;
}

// fused row GEMM + residual + LN (+ optional final linear); one row-task per block-iter
__device__ void projln_stage(const float* __restrict__ A, const float* __restrict__ B,
                             const float* __restrict__ bias, float* __restrict__ t,
                             const float* __restrict__ g, const float* __restrict__ bb,
                             int K, const float* lw, const float* lb, float* outp,
                             char* smem, int blk, int nblk, int tid) {
    float* as  = (float*)smem;        // FFD
    float* ns  = as + FFD;            // DD
    float* red = ns + DD;             // 8
    for (int v = blk; v < NND; v += nblk) {
        for (int i = tid; i < K; i += 256) as[i] = A[(size_t)v * K + i];
        __syncthreads();
        float val = 0.f;
        if (tid < DD) {
            val = bias[tid];
            #pragma unroll 4
            for (int k = 0; k < K; ++k) val += as[k] * B[(size_t)k * DD + tid];
            val += t[(size_t)v * DD + tid];
        }
        float s = wred(val);
        if ((tid & 63) == 0) red[tid >> 6] = s;
        __syncthreads();
        float m = (red[0] + red[1] + red[2]) * (1.f / DD);
        float d = (tid < DD) ? val - m : 0.f;
        s = wred(d * d);
        if ((tid & 63) == 0) red[(tid >> 6) + 4] = s;
        __syncthreads();
        float var = (red[4] + red[5] + red[6]) * (1.f / DD);
        float rs = rsqrtf(var + 1e-5f);
        if (tid < DD) {
            float nv = d * rs * g[tid] + bb[tid];
            t[(size_t)v * DD + tid] = nv;
            ns[tid] = nv;
        }
        __syncthreads();
        if (outp && tid < NCLS) {
            float a = lb[tid];
            for (int k = 0; k < DD; ++k) a += ns[k] * lw[k * NCLS + tid];
            outp[v * NCLS + tid] = a;
        }
        __syncthreads();
    }
}

#define UPD4(ac, V) { ac.x = ac.x * corr + pp * V.x; ac.y = ac.y * corr + pp * V.y; \
                      ac.z = ac.z * corr + pp * V.z; ac.w = ac.w * corr + pp * V.w; }

__global__ __launch_bounds__(256, 2) void k_all(Params p) {
    cg::grid_group gg = cg::this_grid();
    __shared__ __align__(16) char smem[35840];
    const int blk = blockIdx.x, tid = threadIdx.x, nblk = gridDim.x;

    // ================= stage 0a: ChebConv (2 nodes / block-iter) =================
    {
        float (*xs)[5][NNF] = (float (*)[5][NNF])smem;
        int s = tid >> 7, o = tid & 127;
        for (int v = blk; v < NND / 2; v += nblk) {
            int n = v * 2 + s;
            int g = n / LSEQ, i = n - g * LSEQ;
            if (o < 5 * NNF) {
                int k = o / NNF, f = o - k * NNF;
                int pi = i - 2 + k; pi = pi < 0 ? 0 : (pi > LSEQ - 1 ? LSEQ - 1 : pi);
                xs[s][k][f] = p.x[(g * LSEQ + pi) * NNF + f];
            }
            __syncthreads();
            float di  = dinv_path(i);
            float dm1 = dinv_path(i - 1 < 0 ? 0 : i - 1);
            float dp1 = dinv_path(i + 1 > LSEQ - 1 ? LSEQ - 1 : i + 1);
            float dm2 = dinv_path(i - 2 < 0 ? 0 : i - 2);
            float dp2 = dinv_path(i + 2 > LSEQ - 1 ? LSEQ - 1 : i + 2);
            float wmc = (i > 0)        ? -(dm1 * di) : 0.f;
            float wpc = (i < LSEQ - 1) ? -(dp1 * di) : 0.f;
            float wmm = (i - 1 > 0)        ? -(dm2 * dm1) : 0.f;
            float wpm = -(di * dm1);
            float wmp = -(di * dp1);
            float wpp = (i + 1 < LSEQ - 1) ? -(dp2 * dp1) : 0.f;
            float acc = p.cheb_b[o];
            #pragma unroll
            for (int f = 0; f < NNF; ++f) {
                float xm2 = xs[s][0][f], xm1 = xs[s][1][f], x0 = xs[s][2][f],
                      xp1 = xs[s][3][f], xp2 = xs[s][4][f];
                float t1c = wmc * xm1 + wpc * xp1;
                float t1m = wmm * xm2 + wpm * x0;
                float t1p = wmp * x0 + wpp * xp2;
                float t2 = 2.f * (wmc * t1m + wpc * t1p) - x0;
                acc += x0 * p.cheb_w[f * NH + o] + t1c * p.cheb_w[(NNF + f) * NH + o]
                     + t2 * p.cheb_w[(2 * NNF + f) * NH + o];
            }
            p.hA[n * NH + o] = acc;
            __syncthreads();
        }
    }
    __syncthreads();

    // ================= stage 0b: edge encoder + all-layer t1 =================
    {
        float (*eas)[EHD] = (float (*)[EHD])smem;
        for (int v = blk; v < (NE + 63) / 64; v += nblk) {
            int base = v * 64;
            #pragma unroll
            for (int r = 0; r < 8; ++r) {
                int i = tid + r * 256;
                int el = i >> 5, c = i & 31;
                int e = base + el;
                if (e < NE) {
                    float acc = p.ee_b[c];
                    #pragma unroll
                    for (int f = 0; f < NEF; ++f) acc += p.eattr[e * NEF + f] * p.ee_w[f * EHD + c];
                    eas[el][c] = acc;
                }
            }
            __syncthreads();
            for (int l = 0; l < NLAY; ++l) {
                #pragma unroll
                for (int r = 0; r < 8; ++r) {
                    int i = tid + r * 256;
                    int el = i >> 5, c = i & 31;
                    int e = base + el;
                    if (e < NE) {
                        float acc = p.mlp_b1[l * H3D + c];
                        #pragma unroll
                        for (int j = 0; j < EHD; ++j) acc += eas[el][j] * p.mlp_w1[(l * EHD + j) * H3D + c];
                        p.t1all[((size_t)l * NE + e) * H3D + c] = acc;
                    }
                }
            }
            __syncthreads();
        }
    }
    __syncthreads();

    // ================= stage 0c: pack B =================
    {
        bf16 (*tt)[65] = (bf16 (*)[65])smem;
        for (int v = blk; v < 2 * NCT * NLAY; v += nblk) {
            int kt = v & 1, rest = v >> 1;
            int ct = rest % NCT, l = rest / NCT;
            int cc = tid & 63, rr = tid >> 6;
            int colbase = ct * 64;
            #pragma unroll
            for (int rep = 0; rep < 16; ++rep) {
                int kk = rep * 4 + rr;
                int k = kt * 64 + kk;
                int col = colbase + cc;
                float val;
                if (col < 4096) {
                    int j = col >> 7, o = col & 127;
                    val = p.mlp_w2[(size_t)l * 524288 + j * 16384 + k * 128 + o];
                } else if (col < 4224) {
                    val = p.mlp_b2[(size_t)l * 16384 + k * 128 + (col - 4096)];
                } else {
                    val = p.root_w[(size_t)l * 16384 + k * 128 + (col - 4224)];
                }
                tt[kk][cc] = (bf16)val;
            }
            __syncthreads();
            #pragma unroll
            for (int rep = 0; rep < 16; ++rep) {
                int c = rep * 4 + rr;
                p.bpack[((size_t)((l * NCT + ct) * 64 + c)) * 128 + kt * 64 + cc] = tt[cc][c];
            }
            __syncthreads();
        }
    }
    gg.sync();

    // ================= 10 NNConv layers =================
    const float* hcur = p.hA;
    float* hnxt = p.hB;
    for (int l = 0; l < NLAY; ++l) {
        // --- prep: z=(l? gelu(LN(h)):h)->hbf ; newh=(l? h:0)+conv_b ---
        {
            int lane = tid & 63, w4 = tid >> 6;
            for (int v = blk; v < NPAD / 4; v += nblk) {
                int row = v * 4 + w4;
                if (row >= NND) {
                    p.hbf[row * NH + lane] = (bf16)0.f;
                    p.hbf[row * NH + lane + 64] = (bf16)0.f;
                    continue;
                }
                float v0 = hcur[row * NH + lane], v1 = hcur[row * NH + lane + 64];
                float z0 = v0, z1 = v1;
                if (l > 0) {
                    float m = wred(v0 + v1) * (1.f / NH);
                    float d0 = v0 - m, d1 = v1 - m;
                    float var = wred(d0 * d0 + d1 * d1) * (1.f / NH);
                    float rs = rsqrtf(var + 1e-5f);
                    z0 = geluf(d0 * rs * p.ln_g[l * NH + lane] + p.ln_b[l * NH + lane]);
                    z1 = geluf(d1 * rs * p.ln_g[l * NH + lane + 64] + p.ln_b[l * NH + lane + 64]);
                }
                p.hbf[row * NH + lane] = (bf16)z0;
                p.hbf[row * NH + lane + 64] = (bf16)z1;
                float b0 = p.conv_b[l * NH + lane], b1 = p.conv_b[l * NH + lane + 64];
                if (l > 0) { b0 += v0; b1 += v1; }
                hnxt[row * NH + lane] = b0;
                hnxt[row * NH + lane + 64] = b1;
            }
        }
        gg.sync();
        // --- MFMA GEMM: HW = hbf @ bpack[l] ---
        {
            int lane = tid & 63, wv = tid >> 6;
            int r = lane & 15, q = lane >> 4, q8 = q * 8;
            const bf16* bpl = p.bpack + (size_t)l * NCT * 64 * NH;
            for (int v = blk; v < NCT * 14; v += nblk) {
                int ct = v % NCT, mt = v / NCT;
                int m0 = mt * 64 + wv * 16;
                const bf16* Arow = p.hbf + (size_t)(m0 + r) * NH;
                const bf16* Bb = bpl + ((size_t)ct * 64 + r) * NH;
                f32x4 a0 = {0.f,0.f,0.f,0.f}, a1 = a0, a2 = a0, a3 = a0;
                #pragma unroll
                for (int ks = 0; ks < 4; ++ks) {
                    int kb = ks * 32 + q8;
                    bf16x8 av = *(const bf16x8*)(Arow + kb);
                    bf16x8 b0 = *(const bf16x8*)(Bb + 0 * 16 * NH + kb);
                    bf16x8 b1 = *(const bf16x8*)(Bb + 1 * 16 * NH + kb);
                    bf16x8 b2 = *(const bf16x8*)(Bb + 2 * 16 * NH + kb);
                    bf16x8 b3 = *(const bf16x8*)(Bb + 3 * 16 * NH + kb);
                    a0 = __builtin_amdgcn_mfma_f32_16x16x32_bf16(av, b0, a0, 0, 0, 0);
                    a1 = __builtin_amdgcn_mfma_f32_16x16x32_bf16(av, b1, a1, 0, 0, 0);
                    a2 = __builtin_amdgcn_mfma_f32_16x16x32_bf16(av, b2, a2, 0, 0, 0);
                    a3 = __builtin_amdgcn_mfma_f32_16x16x32_bf16(av, b3, a3, 0, 0, 0);
                }
                int cb = ct * 64;
                #pragma unroll
                for (int reg = 0; reg < 4; ++reg) {
                    bf16* Crow = p.HW + (size_t)(m0 + q * 4 + reg) * NCOLS + cb;
                    Crow[0 * 16 + r] = (bf16)a0[reg];
                    Crow[1 * 16 + r] = (bf16)a1[reg];
                    Crow[2 * 16 + r] = (bf16)a2[reg];
                    Crow[3 * 16 + r] = (bf16)a3[reg];
                }
            }
        }
        gg.sync();
        // --- edge contraction + aggregation (+root), 2 tasks / block-iter ---
        {
            float (*ts)[H3D] = (float (*)[H3D])smem;
            const float* t1l = p.t1all + (size_t)l * NE * H3D;
            int s2 = tid >> 7, o = tid & 127;
            for (int v = blk; v < (NE + NND) / 2; v += nblk) {
                int t = v * 2 + s2;
                if (t < NE && o < H3D) ts[s2][o] = t1l[t * H3D + o];
                __syncthreads();
                if (t < NE) {
                    int s = p.ei[t], d = p.ei[NE + t];
                    const bf16* row = p.HW + (size_t)s * NCOLS;
                    float acc = (float)row[4096 + o];
                    #pragma unroll
                    for (int j = 0; j < H3D; ++j) acc += ts[s2][j] * (float)row[j * NH + o];
                    atomicAdd(&hnxt[d * NH + o], acc);
                } else {
                    int n = t - NE;
                    atomicAdd(&hnxt[n * NH + o], (float)p.HW[(size_t)n * NCOLS + 4224 + o]);
                }
                __syncthreads();
            }
        }
        gg.sync();
        const float* tmp = hcur; hcur = hnxt; hnxt = (float*)tmp;
    }

    // ================= final gelu(LN) + positional concat =================
    {
        int lane = tid & 63, w4 = tid >> 6;
        for (int v = blk; v < NND / 4 + 1; v += nblk) {
            int n = v * 4 + w4;
            if (n >= NND) continue;
            float v0 = hcur[n * NH + lane], v1 = hcur[n * NH + lane + 64];
            float m = wred(v0 + v1) * (1.f / NH);
            float d0 = v0 - m, d1 = v1 - m;
            float var = wred(d0 * d0 + d1 * d1) * (1.f / NH);
            float rs = rsqrtf(var + 1e-5f);
            p.tbuf[n * DD + lane]      = geluf(d0 * rs * p.ln_g[lane] + p.ln_b[lane]);
            p.tbuf[n * DD + lane + 64] = geluf(d1 * rs * p.ln_g[lane + 64] + p.ln_b[lane + 64]);
            if (lane < PCD) {
                int qq = n % LSEQ;
                float twoi = (float)(lane & ~1);
                float ang = (float)qq * expf(-twoi * 0.28782313662425572f);
                p.tbuf[n * DD + NH + lane] = (lane & 1) ? cosf(ang) : sinf(ang);
            }
        }
    }
    gg.sync();

    // ================= transformer encoder =================
    for (int tl = 0; tl < TLAY; ++tl) {
        // --- qkv projection ---
        {
            const float* W = p.ain_w + (size_t)tl * DD * 3 * DD;
            const float* bi = p.ain_b + (size_t)tl * 3 * DD;
            for (int v = blk; v < 8 * 214; v += nblk) {
                int cbk = v & 7, rb = v >> 3;
                int col = cbk * 64 + (tid & 63);
                int row = rb * 4 + (tid >> 6);
                if (col < 3 * DD) {
                    float acc = bi[col];
                    const float* a = p.tbuf + (size_t)row * DD;
                    #pragma unroll 8
                    for (int k = 0; k < DD; ++k) acc += a[k] * W[(size_t)k * 3 * DD + col];
                    p.qkv[(size_t)row * 3 * DD + col] = acc;
                }
            }
        }
        gg.sync();
        // --- attention: 2 bh per block, both q-tiles ---
        {
            if (blk < 32) {
                float4* Ks = (float4*)smem;          // [2][LSEQ*5]
                float4* Vs = Ks + 2 * LSEQ * 5;
                for (int s = 0; s < 2; ++s) {
                    int bh = blk * 2 + s;
                    int b = bh >> 3, hh = bh & 7;
                    for (int i = tid; i < LSEQ * 5; i += 256) {
                        int kq = i / 5, c4 = i - kq * 5;
                        const float* rowp = p.qkv + (size_t)(b * LSEQ + kq) * (3 * DD) + hh * HDD;
                        Ks[s * LSEQ * 5 + i] = ((const float4*)(rowp + DD))[c4];
                        Vs[s * LSEQ * 5 + i] = ((const float4*)(rowp + 2 * DD))[c4];
                    }
                }
                __syncthreads();
                int sub = tid >> 6;
                int s = sub >> 1, qt = sub & 1;
                int bh = blk * 2 + s;
                int b = bh >> 3, hh = bh & 7;
                int q = qt * 64 + (tid & 63);
                if (q < LSEQ) {
                    const float4* qp = (const float4*)(p.qkv + (size_t)(b * LSEQ + q) * (3 * DD) + hh * HDD);
                    float4 q0 = qp[0], q1 = qp[1], q2 = qp[2], q3 = qp[3], q4 = qp[4];
                    const float scale = 0.22360679774997896f;
                    float mx = -3.0e38f, sum = 0.f;
                    float4 zz = {0.f,0.f,0.f,0.f};
                    float4 ac0 = zz, ac1 = zz, ac2 = zz, ac3 = zz, ac4 = zz;
                    const float4* Kb = Ks + s * LSEQ * 5;
                    const float4* Vb = Vs + s * LSEQ * 5;
                    for (int k = 0; k < LSEQ; ++k) {
                        const float4* kp = Kb + k * 5;
                        float4 K0 = kp[0], K1 = kp[1], K2 = kp[2], K3 = kp[3], K4 = kp[4];
                        float a0 = q0.x*K0.x + q0.y*K0.y + q0.z*K0.z + q0.w*K0.w;
                        float a1 = q1.x*K1.x + q1.y*K1.y + q1.z*K1.z + q1.w*K1.w;
                        float a2 = q2.x*K2.x + q2.y*K2.y + q2.z*K2.z + q2.w*K2.w;
                        float a3 = q3.x*K3.x + q3.y*K3.y + q3.z*K3.z + q3.w*K3.w;
                        float a4 = q4.x*K4.x + q4.y*K4.y + q4.z*K4.z + q4.w*K4.w;
                        float sc = (((a0 + a1) + (a2 + a3)) + a4) * scale;
                        float mn = fmaxf(mx, sc);
                        float corr = __expf(mx - mn);
                        float pp = __expf(sc - mn);
                        mx = mn;
                        sum = sum * corr + pp;
                        const float4* vp = Vb + k * 5;
                        float4 V0 = vp[0], V1 = vp[1], V2 = vp[2], V3 = vp[3], V4 = vp[4];
                        UPD4(ac0, V0); UPD4(ac1, V1); UPD4(ac2, V2); UPD4(ac3, V3); UPD4(ac4, V4);
                    }
                    float inv = 1.f / sum;
                    float4* op = (float4*)(p.abuf + (size_t)(b * LSEQ + q) * DD + hh * HDD);
                    float4 o0 = {ac0.x*inv, ac0.y*inv, ac0.z*inv, ac0.w*inv};
                    float4 o1 = {ac1.x*inv, ac1.y*inv, ac1.z*inv, ac1.w*inv};
                    float4 o2 = {ac2.x*inv, ac2.y*inv, ac2.z*inv, ac2.w*inv};
                    float4 o3 = {ac3.x*inv, ac3.y*inv, ac3.z*inv, ac3.w*inv};
                    float4 o4 = {ac4.x*inv, ac4.y*inv, ac4.z*inv, ac4.w*inv};
                    op[0] = o0; op[1] = o1; op[2] = o2; op[3] = o3; op[4] = o4;
                }
            }
        }
        gg.sync();
        // --- attn out proj + residual + LN ---
        projln_stage(p.abuf, p.aow + (size_t)tl * DD * DD, p.aob + (size_t)tl * DD,
                     p.tbuf, p.t1g + (size_t)tl * DD, p.t1b + (size_t)tl * DD, DD,
                     nullptr, nullptr, nullptr, smem, blk, nblk, tid);
        gg.sync();
        // --- FFN-1 (relu) ---
        {
            const float* W1 = p.ffw1 + (size_t)tl * DD * FFD;
            const float* bb1 = p.ffb1 + (size_t)tl * FFD;
            for (int v = blk; v < 4 * 214; v += nblk) {
                int cbk = v & 3, rb = v >> 2;
                int col = cbk * 64 + (tid & 63);
                int row = rb * 4 + (tid >> 6);
                float acc = bb1[col];
                const float* a = p.tbuf + (size_t)row * DD;
                #pragma unroll 8
                for (int k = 0; k < DD; ++k) acc += a[k] * W1[(size_t)k * FFD + col];
                p.f1[(size_t)row * FFD + col] = fmaxf(acc, 0.f);
            }
        }
        gg.sync();
        // --- FFN-2 + residual + LN (+ final linear on last layer) ---
        bool last = (tl == TLAY - 1);
        projln_stage(p.f1, p.ffw2 + (size_t)tl * FFD * DD, p.ffb2 + (size_t)tl * DD,
                     p.tbuf, p.t2g + (size_t)tl * DD, p.t2b + (size_t)tl * DD, FFD,
                     last ? p.lin_w : nullptr, last ? p.lin_b : nullptr,
                     last ? p.out : nullptr, smem, blk, nblk, tid);
        gg.sync();
    }
}

extern "C" void kernel_launch(void* const* d_in, const int* in_sizes, int n_in,
                              void* d_out, int out_size, void* d_ws, size_t ws_size,
                              hipStream_t stream) {
    (void)in_sizes; (void)n_in; (void)out_size; (void)ws_size;
    Params p;
    p.x      = (const float*)d_in[0];
    p.eattr  = (const float*)d_in[1];
    p.cheb_w = (const float*)d_in[2];
    p.cheb_b = (const float*)d_in[3];
    p.ee_w   = (const float*)d_in[4];
    p.ee_b   = (const float*)d_in[5];
    p.mlp_w1 = (const float*)d_in[6];
    p.mlp_b1 = (const float*)d_in[7];
    p.mlp_w2 = (const float*)d_in[8];
    p.mlp_b2 = (const float*)d_in[9];
    p.root_w = (const float*)d_in[10];
    p.conv_b = (const float*)d_in[11];
    p.ln_g   = (const float*)d_in[12];
    p.ln_b   = (const float*)d_in[13];
    p.ain_w  = (const float*)d_in[14];
    p.ain_b  = (const float*)d_in[15];
    p.aow    = (const float*)d_in[16];
    p.aob    = (const float*)d_in[17];
    p.ffw1   = (const float*)d_in[18];
    p.ffb1   = (const float*)d_in[19];
    p.ffw2   = (const float*)d_in[20];
    p.ffb2   = (const float*)d_in[21];
    p.t1g    = (const float*)d_in[22];
    p.t1b    = (const float*)d_in[23];
    p.t2g    = (const float*)d_in[24];
    p.t2b    = (const float*)d_in[25];
    p.lin_w  = (const float*)d_in[26];
    p.lin_b  = (const float*)d_in[27];
    p.ei     = (const int*)d_in[29];

    char* w = (char*)d_ws;
    size_t off = 0;
    auto alloc = [&](size_t bytes) -> void* {
        void* ptr = w + off;
        off += (bytes + 255) & ~(size_t)255;
        return ptr;
    };
    p.bpack = (bf16*)alloc((size_t)NLAY * NCT * 64 * NH * 2);
    p.t1all = (float*)alloc((size_t)NLAY * NE * H3D * 4);
    p.hA    = (float*)alloc((size_t)NND * NH * 4);
    p.hB    = (float*)alloc((size_t)NND * NH * 4);
    p.hbf   = (bf16*)alloc((size_t)NPAD * NH * 2);
    p.HW    = (bf16*)alloc((size_t)NPAD * NCOLS * 2);
    p.tbuf  = (float*)alloc((size_t)NND * DD * 4);
    p.qkv   = (float*)alloc((size_t)NND * 3 * DD * 4);
    p.abuf  = (float*)alloc((size_t)NND * DD * 4);
    p.f1    = (float*)alloc((size_t)NND * FFD * 4);
    p.out   = (float*)d_out;

    int maxb = 0;
    hipOccupancyMaxActiveBlocksPerMultiprocessor(&maxb, k_all, 256, 0);
    if (maxb < 1) maxb = 1;
    int grid = maxb * 256;
    if (grid > 1024) grid = 1024;
    void* args[] = { &p };
    hipLaunchCooperativeKernel(k_all, dim3(grid), dim3(256), args, 0u, stream);
}

// Round 6
// 655.910 us; speedup vs baseline: 3.4306x; 3.4306x over previous
//
#include <hip/hip_runtime.h>
#include <hip/hip_bf16.h>
#include <math.h>

// ---------------- problem constants ----------------
#define BSZ   8
#define LSEQ  107
#define NNF   17
#define NEF   9
#define NH    128
#define EHD   32
#define H3D   32
#define NLAY  10
#define PCD   32
#define TLAY  3
#define THD   8
#define FFD   256
#define NCLS  3
#define DD    160          // NH + PC
#define HDD   20           // D / TH
#define NND   856          // nodes
#define NPAD  896          // padded to 14*64 for GEMM
#define NE    2896         // edges
#define NCOLS 4352         // 4096 (msg) + 128 (b2 part) + 128 (root part)
#define NCT   68           // 4352 / 64 column tiles

typedef __bf16 bf16;
typedef __bf16 bf16x8 __attribute__((ext_vector_type(8)));
typedef float  f32x4  __attribute__((ext_vector_type(4)));

__device__ __forceinline__ float geluf(float z) {
    return 0.5f * z * (1.0f + erff(z * 0.70710678118654752f));
}
__device__ __forceinline__ float wred(float v) {
    #pragma unroll
    for (int o = 32; o; o >>= 1) v += __shfl_xor(v, o, 64);
    return v;
}
__device__ __forceinline__ float dinv_path(int n) {
    return (n == 0 || n == LSEQ - 1) ? 1.0f : 0.70710678118654752f;
}

// ---------------- ChebConv: one block per node, 5-point stencil (R4-validated) ----------------
__global__ __launch_bounds__(128) void k_cheb3(const float* __restrict__ x,
                                               const float* __restrict__ cw,
                                               const float* __restrict__ cb,
                                               float* __restrict__ h0) {
    __shared__ float xs[5][NNF];
    int n = blockIdx.x, o = threadIdx.x;
    int g = n / LSEQ, i = n - g * LSEQ;
    if (o < 5 * NNF) {
        int k = o / NNF, f = o - k * NNF;
        int p = i - 2 + k;
        p = p < 0 ? 0 : (p > LSEQ - 1 ? LSEQ - 1 : p);
        xs[k][f] = x[(g * LSEQ + p) * NNF + f];
    }
    __syncthreads();
    float di  = dinv_path(i);
    float dm1 = dinv_path(i - 1 < 0 ? 0 : i - 1);
    float dp1 = dinv_path(i + 1 > LSEQ - 1 ? LSEQ - 1 : i + 1);
    float dm2 = dinv_path(i - 2 < 0 ? 0 : i - 2);
    float dp2 = dinv_path(i + 2 > LSEQ - 1 ? LSEQ - 1 : i + 2);
    float wmc = (i > 0)        ? -(dm1 * di) : 0.f;
    float wpc = (i < LSEQ - 1) ? -(dp1 * di) : 0.f;
    float wmm = (i - 1 > 0)        ? -(dm2 * dm1) : 0.f;
    float wpm = -(di * dm1);
    float wmp = -(di * dp1);
    float wpp = (i + 1 < LSEQ - 1) ? -(dp2 * dp1) : 0.f;
    float acc = cb[o];
    #pragma unroll
    for (int f = 0; f < NNF; ++f) {
        float xm2 = xs[0][f], xm1 = xs[1][f], x0 = xs[2][f], xp1 = xs[3][f], xp2 = xs[4][f];
        float t1c = wmc * xm1 + wpc * xp1;
        float t1m = wmm * xm2 + wpm * x0;
        float t1p = wmp * x0 + wpp * xp2;
        float t2 = 2.f * (wmc * t1m + wpc * t1p) - x0;
        acc += x0 * cw[f * NH + o] + t1c * cw[(NNF + f) * NH + o]
             + t2 * cw[(2 * NNF + f) * NH + o];
    }
    h0[n * NH + o] = acc;
}

// ---------------- edge encoder + all-layer t1 (R2-validated, big grids) ----------------
__global__ void k_ea(const float* eattr, const float* eew, const float* eeb, float* ea) {
    int idx = blockIdx.x * 256 + threadIdx.x;
    if (idx >= NE * EHD) return;
    int e = idx >> 5, c = idx & 31;
    float acc = eeb[c];
    #pragma unroll
    for (int f = 0; f < NEF; ++f) acc += eattr[e * NEF + f] * eew[f * EHD + c];
    ea[idx] = acc;
}
__global__ void k_t1(const float* ea, const float* w1, const float* b1, float* t1) {
    int idx = blockIdx.x * 256 + threadIdx.x;
    if (idx >= NLAY * NE * H3D) return;
    int c = idx & 31;
    int le = idx >> 5;
    int e = le % NE, l = le / NE;
    float acc = b1[l * H3D + c];
    #pragma unroll
    for (int j = 0; j < EHD; ++j) acc += ea[e * EHD + j] * w1[(l * EHD + j) * H3D + c];
    t1[idx] = acc;
}

// ---------------- pack B: [l][col][k] bf16; col = j*128+o | 4096+o (b2) | 4224+o (root) ----------------
__global__ void k_pack(const float* w2, const float* b2, const float* rootw, bf16* bp) {
    __shared__ bf16 t[64][65];
    int l = blockIdx.z, ct = blockIdx.y, kt = blockIdx.x;
    int tid = threadIdx.x;
    int cc = tid & 63, rr = tid >> 6;
    int colbase = ct * 64;
    #pragma unroll
    for (int rep = 0; rep < 16; ++rep) {
        int kk = rep * 4 + rr;
        int k = kt * 64 + kk;
        int col = colbase + cc;
        float v;
        if (col < 4096) {
            int j = col >> 7, o = col & 127;
            v = w2[(size_t)l * 524288 + j * 16384 + k * 128 + o];
        } else if (col < 4224) {
            v = b2[(size_t)l * 16384 + k * 128 + (col - 4096)];
        } else {
            v = rootw[(size_t)l * 16384 + k * 128 + (col - 4224)];
        }
        t[kk][cc] = (bf16)v;
    }
    __syncthreads();
    #pragma unroll
    for (int rep = 0; rep < 16; ++rep) {
        int c = rep * 4 + rr;
        bp[((size_t)((l * NCT + ct) * 64 + c)) * 128 + kt * 64 + cc] = t[cc][c];
    }
}

// ---------------- per-layer prep (R2-validated) ----------------
__global__ void k_prep(const float* h, const float* lng, const float* lnb, const float* cbias,
                       int l, bf16* hbf, float* newh) {
    int n = blockIdx.x, lane = threadIdx.x;
    if (n >= NND) {
        hbf[n * NH + lane] = (bf16)0.f;
        hbf[n * NH + lane + 64] = (bf16)0.f;
        return;
    }
    float v0 = h[n * NH + lane], v1 = h[n * NH + lane + 64];
    float z0 = v0, z1 = v1;
    if (l > 0) {
        float m = wred(v0 + v1) * (1.f / NH);
        float d0 = v0 - m, d1 = v1 - m;
        float var = wred(d0 * d0 + d1 * d1) * (1.f / NH);
        float rs = rsqrtf(var + 1e-5f);
        z0 = geluf(d0 * rs * lng[l * NH + lane] + lnb[l * NH + lane]);
        z1 = geluf(d1 * rs * lng[l * NH + lane + 64] + lnb[l * NH + lane + 64]);
    }
    hbf[n * NH + lane] = (bf16)z0;
    hbf[n * NH + lane + 64] = (bf16)z1;
    float b0 = cbias[l * NH + lane], b1 = cbias[l * NH + lane + 64];
    if (l > 0) { b0 += v0; b1 += v1; }
    newh[n * NH + lane] = b0;
    newh[n * NH + lane + 64] = b1;
}

// ---------------- MFMA GEMM: HW[896 x 4352](bf16) = hbf[896 x 128] @ Bpack (R2-validated) ----------------
__global__ __launch_bounds__(256) void k_gemm(const bf16* __restrict__ hbf,
                                              const bf16* __restrict__ bp,
                                              bf16* __restrict__ HW) {
    int lane = threadIdx.x & 63, wv = threadIdx.x >> 6;
    int m0 = blockIdx.y * 64 + wv * 16;
    int ct = blockIdx.x;
    int r = lane & 15, q = lane >> 4;
    const bf16* Arow = hbf + (size_t)(m0 + r) * NH;
    const bf16* Bb = bp + ((size_t)ct * 64 + r) * NH;
    f32x4 a0 = {0.f,0.f,0.f,0.f}, a1 = a0, a2 = a0, a3 = a0;
    int q8 = q * 8;
    #pragma unroll
    for (int ks = 0; ks < 4; ++ks) {
        int kb = ks * 32 + q8;
        bf16x8 av = *(const bf16x8*)(Arow + kb);
        bf16x8 b0 = *(const bf16x8*)(Bb + 0 * 16 * NH + kb);
        bf16x8 b1 = *(const bf16x8*)(Bb + 1 * 16 * NH + kb);
        bf16x8 b2 = *(const bf16x8*)(Bb + 2 * 16 * NH + kb);
        bf16x8 b3 = *(const bf16x8*)(Bb + 3 * 16 * NH + kb);
        a0 = __builtin_amdgcn_mfma_f32_16x16x32_bf16(av, b0, a0, 0, 0, 0);
        a1 = __builtin_amdgcn_mfma_f32_16x16x32_bf16(av, b1, a1, 0, 0, 0);
        a2 = __builtin_amdgcn_mfma_f32_16x16x32_bf16(av, b2, a2, 0, 0, 0);
        a3 = __builtin_amdgcn_mfma_f32_16x16x32_bf16(av, b3, a3, 0, 0, 0);
    }
    int cb = ct * 64;
    #pragma unroll
    for (int reg = 0; reg < 4; ++reg) {
        bf16* Crow = HW + (size_t)(m0 + q * 4 + reg) * NCOLS + cb;
        Crow[0 * 16 + r] = (bf16)a0[reg];
        Crow[1 * 16 + r] = (bf16)a1[reg];
        Crow[2 * 16 + r] = (bf16)a2[reg];
        Crow[3 * 16 + r] = (bf16)a3[reg];
    }
}

// ---------------- edge contraction + aggregation (R2-validated) ----------------
__global__ void k_edge(const int* ei, const float* t1l, const bf16* __restrict__ HW,
                       float* newh) {
    __shared__ float ts[H3D];
    int blk = blockIdx.x, o = threadIdx.x;
    if (blk < NE) {
        if (o < H3D) ts[o] = t1l[blk * H3D + o];
        __syncthreads();
        int s = ei[blk], d = ei[NE + blk];
        const bf16* row = HW + (size_t)s * NCOLS;
        float acc = (float)row[4096 + o];
        #pragma unroll
        for (int j = 0; j < H3D; ++j) acc += ts[j] * (float)row[j * NH + o];
        atomicAdd(&newh[d * NH + o], acc);
    } else {
        int n = blk - NE;
        atomicAdd(&newh[n * NH + o], (float)HW[(size_t)n * NCOLS + 4224 + o]);
    }
}

// ---------------- final gelu(LN) + positional concat (R2-validated) ----------------
__global__ void k_fc(const float* h, const float* lng, const float* lnb, float* t) {
    int n = blockIdx.x, lane = threadIdx.x;
    float v0 = h[n * NH + lane], v1 = h[n * NH + lane + 64];
    float m = wred(v0 + v1) * (1.f / NH);
    float d0 = v0 - m, d1 = v1 - m;
    float var = wred(d0 * d0 + d1 * d1) * (1.f / NH);
    float rs = rsqrtf(var + 1e-5f);
    t[n * DD + lane]      = geluf(d0 * rs * lng[lane] + lnb[lane]);
    t[n * DD + lane + 64] = geluf(d1 * rs * lng[lane + 64] + lnb[lane + 64]);
    if (lane < PCD) {
        int qq = n % LSEQ;
        float twoi = (float)(lane & ~1);
        float ang = (float)qq * expf(-twoi * 0.28782313662425572f);
        t[n * DD + NH + lane] = (lane & 1) ? cosf(ang) : sinf(ang);
    }
}

// ---------------- generic small GEMM (R2-validated) ----------------
__global__ void k_mm(const float* __restrict__ A, const float* __restrict__ B,
                     const float* __restrict__ bias, float* __restrict__ C,
                     int M, int K, int Ncols, int act) {
    int col = blockIdx.x * 64 + threadIdx.x;
    int row = blockIdx.y * 4 + threadIdx.y;
    if (row >= M || col >= Ncols) return;
    float acc = bias[col];
    const float* a = A + (size_t)row * K;
    const float* b = B + col;
    #pragma unroll 8
    for (int k = 0; k < K; ++k) acc += a[k] * b[(size_t)k * Ncols];
    if (act) acc = fmaxf(acc, 0.f);
    C[(size_t)row * Ncols + col] = acc;
}

// ---------------- attention v2 (R3-validated): online softmax, float4, 1 wave/block ----------------
#define UPD4(ac, V) { ac.x = ac.x * corr + p * V.x; ac.y = ac.y * corr + p * V.y; \
                      ac.z = ac.z * corr + p * V.z; ac.w = ac.w * corr + p * V.w; }
__global__ __launch_bounds__(64) void k_attn(const float* __restrict__ qkv,
                                             float* __restrict__ aout) {
    __shared__ float4 Ks4[LSEQ * 5], Vs4[LSEQ * 5];
    int bh = blockIdx.x;
    int b = bh >> 3, hh = bh & 7;
    int tid = threadIdx.x;
    for (int i = tid; i < LSEQ * 5; i += 64) {
        int kq = i / 5, c4 = i - kq * 5;
        const float* rowp = qkv + (size_t)(b * LSEQ + kq) * (3 * DD) + hh * HDD;
        Ks4[i] = ((const float4*)(rowp + DD))[c4];
        Vs4[i] = ((const float4*)(rowp + 2 * DD))[c4];
    }
    __syncthreads();
    int q = blockIdx.y * 64 + tid;
    if (q >= LSEQ) return;
    const float4* qp = (const float4*)(qkv + (size_t)(b * LSEQ + q) * (3 * DD) + hh * HDD);
    float4 q0 = qp[0], q1 = qp[1], q2 = qp[2], q3 = qp[3], q4 = qp[4];
    const float scale = 0.22360679774997896f;
    float mx = -3.0e38f, sum = 0.f;
    float4 z = {0.f, 0.f, 0.f, 0.f};
    float4 ac0 = z, ac1 = z, ac2 = z, ac3 = z, ac4 = z;
    for (int k = 0; k < LSEQ; ++k) {
        const float4* kp = Ks4 + k * 5;
        float4 K0 = kp[0], K1 = kp[1], K2 = kp[2], K3 = kp[3], K4 = kp[4];
        float a0 = q0.x * K0.x + q0.y * K0.y + q0.z * K0.z + q0.w * K0.w;
        float a1 = q1.x * K1.x + q1.y * K1.y + q1.z * K1.z + q1.w * K1.w;
        float a2 = q2.x * K2.x + q2.y * K2.y + q2.z * K2.z + q2.w * K2.w;
        float a3 = q3.x * K3.x + q3.y * K3.y + q3.z * K3.z + q3.w * K3.w;
        float a4 = q4.x * K4.x + q4.y * K4.y + q4.z * K4.z + q4.w * K4.w;
        float s = (((a0 + a1) + (a2 + a3)) + a4) * scale;
        float mn = fmaxf(mx, s);
        float corr = __expf(mx - mn);
        float p = __expf(s - mn);
        mx = mn;
        sum = sum * corr + p;
        const float4* vp = Vs4 + k * 5;
        float4 V0 = vp[0], V1 = vp[1], V2 = vp[2], V3 = vp[3], V4 = vp[4];
        UPD4(ac0, V0); UPD4(ac1, V1); UPD4(ac2, V2); UPD4(ac3, V3); UPD4(ac4, V4);
    }
    float inv = 1.f / sum;
    float4* op = (float4*)(aout + (size_t)(b * LSEQ + q) * DD + hh * HDD);
    float4 o0 = {ac0.x * inv, ac0.y * inv, ac0.z * inv, ac0.w * inv};
    float4 o1 = {ac1.x * inv, ac1.y * inv, ac1.z * inv, ac1.w * inv};
    float4 o2 = {ac2.x * inv, ac2.y * inv, ac2.z * inv, ac2.w * inv};
    float4 o3 = {ac3.x * inv, ac3.y * inv, ac3.z * inv, ac3.w * inv};
    float4 o4 = {ac4.x * inv, ac4.y * inv, ac4.z * inv, ac4.w * inv};
    op[0] = o0; op[1] = o1; op[2] = o2; op[3] = o3; op[4] = o4;
}

// ---------------- t = LN(t + delta) (R2-validated) ----------------
__global__ void k_addln(float* t, const float* delta, const float* g, const float* b) {
    int n = blockIdx.x, lane = threadIdx.x;
    int c0 = lane, c1 = lane + 64, c2 = lane + 128;
    float v0 = t[n * DD + c0] + delta[n * DD + c0];
    float v1 = t[n * DD + c1] + delta[n * DD + c1];
    float v2 = (lane < 32) ? (t[n * DD + c2] + delta[n * DD + c2]) : 0.f;
    float m = wred(v0 + v1 + v2) * (1.f / DD);
    float d0 = v0 - m, d1 = v1 - m, d2 = (lane < 32) ? (v2 - m) : 0.f;
    float var = wred(d0 * d0 + d1 * d1 + d2 * d2) * (1.f / DD);
    float rs = rsqrtf(var + 1e-5f);
    t[n * DD + c0] = d0 * rs * g[c0] + b[c0];
    t[n * DD + c1] = d1 * rs * g[c1] + b[c1];
    if (lane < 32) t[n * DD + c2] = d2 * rs * g[c2] + b[c2];
}

// ---------------- final linear (R2-validated) ----------------
__global__ void k_lin(const float* t, const float* lw, const float* lb, float* out) {
    int idx = blockIdx.x * 256 + threadIdx.x;
    if (idx >= NND * NCLS) return;
    int n = idx / NCLS, c = idx - n * NCLS;
    float acc = lb[c];
    #pragma unroll 8
    for (int k = 0; k < DD; ++k) acc += t[n * DD + k] * lw[k * NCLS + c];
    out[idx] = acc;
}

extern "C" void kernel_launch(void* const* d_in, const int* in_sizes, int n_in,
                              void* d_out, int out_size, void* d_ws, size_t ws_size,
                              hipStream_t stream) {
    (void)in_sizes; (void)n_in; (void)out_size; (void)ws_size;
    const float* x      = (const float*)d_in[0];
    const float* eattr  = (const float*)d_in[1];
    const float* cheb_w = (const float*)d_in[2];
    const float* cheb_b = (const float*)d_in[3];
    const float* ee_w   = (const float*)d_in[4];
    const float* ee_b   = (const float*)d_in[5];
    const float* mlp_w1 = (const float*)d_in[6];
    const float* mlp_b1 = (const float*)d_in[7];
    const float* mlp_w2 = (const float*)d_in[8];
    const float* mlp_b2 = (const float*)d_in[9];
    const float* root_w = (const float*)d_in[10];
    const float* conv_b = (const float*)d_in[11];
    const float* ln_g   = (const float*)d_in[12];
    const float* ln_b   = (const float*)d_in[13];
    const float* ain_w  = (const float*)d_in[14];
    const float* ain_b  = (const float*)d_in[15];
    const float* aow    = (const float*)d_in[16];
    const float* aob    = (const float*)d_in[17];
    const float* ffw1   = (const float*)d_in[18];
    const float* ffb1   = (const float*)d_in[19];
    const float* ffw2   = (const float*)d_in[20];
    const float* ffb2   = (const float*)d_in[21];
    const float* t1g    = (const float*)d_in[22];
    const float* t1b    = (const float*)d_in[23];
    const float* t2g    = (const float*)d_in[24];
    const float* t2b    = (const float*)d_in[25];
    const float* lin_w  = (const float*)d_in[26];
    const float* lin_b  = (const float*)d_in[27];
    const int* ei       = (const int*)d_in[29];

    char* w = (char*)d_ws;
    size_t off = 0;
    auto alloc = [&](size_t bytes) -> void* {
        void* p = w + off;
        off += (bytes + 255) & ~(size_t)255;
        return p;
    };
    bf16*  bpack = (bf16*)alloc((size_t)NLAY * NCT * 64 * NH * 2);
    float* t1all = (float*)alloc((size_t)NLAY * NE * H3D * 4);
    float* ea    = (float*)alloc((size_t)NE * EHD * 4);
    float* hA    = (float*)alloc((size_t)NND * NH * 4);
    float* hB    = (float*)alloc((size_t)NND * NH * 4);
    bf16*  hbf   = (bf16*)alloc((size_t)NPAD * NH * 2);
    bf16*  HW    = (bf16*)alloc((size_t)NPAD * NCOLS * 2);
    float* tbuf  = (float*)alloc((size_t)NND * DD * 4);
    float* qkv   = (float*)alloc((size_t)NND * 3 * DD * 4);
    float* abuf  = (float*)alloc((size_t)NND * DD * 4);
    float* proj  = (float*)alloc((size_t)NND * DD * 4);
    float* f1    = (float*)alloc((size_t)NND * FFD * 4);

    // --- ChebConv (one block per node, stencil form; no memset needed) ---
    k_cheb3<<<NND, 128, 0, stream>>>(x, cheb_w, cheb_b, hA);

    // --- edge encoder, all-layer t1, weight pack (R2 forms, big grids) ---
    k_ea<<<(NE * EHD + 255) / 256, 256, 0, stream>>>(eattr, ee_w, ee_b, ea);
    k_t1<<<(NLAY * NE * H3D + 255) / 256, 256, 0, stream>>>(ea, mlp_w1, mlp_b1, t1all);
    k_pack<<<dim3(2, NCT, NLAY), 256, 0, stream>>>(mlp_w2, mlp_b2, root_w, bpack);

    // --- 10 NNConv layers ---
    float* hcur = hA;
    float* hnxt = hB;
    for (int l = 0; l < NLAY; ++l) {
        k_prep<<<NPAD, 64, 0, stream>>>(hcur, ln_g, ln_b, conv_b, l, hbf, hnxt);
        k_gemm<<<dim3(NCT, 14), 256, 0, stream>>>(hbf, bpack + (size_t)l * NCT * 64 * NH, HW);
        k_edge<<<NE + NND, NH, 0, stream>>>(ei, t1all + (size_t)l * NE * H3D, HW, hnxt);
        float* tmp = hcur; hcur = hnxt; hnxt = tmp;
    }

    // --- final gelu(LN) + pos concat ---
    k_fc<<<NND, 64, 0, stream>>>(hcur, ln_g, ln_b, tbuf);

    // --- transformer encoder (3 layers, post-norm), R2 forms + attn v2 ---
    for (int tl = 0; tl < TLAY; ++tl) {
        k_mm<<<dim3(8, 214), dim3(64, 4), 0, stream>>>(tbuf, ain_w + (size_t)tl * DD * 3 * DD,
                                                       ain_b + (size_t)tl * 3 * DD, qkv,
                                                       NND, DD, 3 * DD, 0);
        k_attn<<<dim3(BSZ * THD, 2), 64, 0, stream>>>(qkv, abuf);
        k_mm<<<dim3(3, 214), dim3(64, 4), 0, stream>>>(abuf, aow + (size_t)tl * DD * DD,
                                                       aob + (size_t)tl * DD, proj,
                                                       NND, DD, DD, 0);
        k_addln<<<NND, 64, 0, stream>>>(tbuf, proj, t1g + (size_t)tl * DD, t1b + (size_t)tl * DD);
        k_mm<<<dim3(4, 214), dim3(64, 4), 0, stream>>>(tbuf, ffw1 + (size_t)tl * DD * FFD,
                                                       ffb1 + (size_t)tl * FFD, f1,
                                                       NND, DD, FFD, 1);
        k_mm<<<dim3(3, 214), dim3(64, 4), 0, stream>>>(f1, ffw2 + (size_t)tl * FFD * DD,
                                                       ffb2 + (size_t)tl * DD, proj,
                                                       NND, FFD, DD, 0);
        k_addln<<<NND, 64, 0, stream>>>(tbuf, proj, t2g + (size_t)tl * DD, t2b + (size_t)tl * DD);
    }

    // --- final linear ---
    k_lin<<<(NND * NCLS + 255) / 256, 256, 0, stream>>>(tbuf, lin_w, lin_b, (float*)d_out);
}

// Round 7
// 649.457 us; speedup vs baseline: 3.4647x; 1.0099x over previous
//
#include <hip/hip_runtime.h>
#include <hip/hip_bf16.h>
#include <math.h>

// ---------------- problem constants ----------------
#define BSZ   8
#define LSEQ  107
#define NNF   17
#define NEF   9
#define NH    128
#define EHD   32
#define H3D   32
#define NLAY  10
#define PCD   32
#define TLAY  3
#define THD   8
#define FFD   256
#define NCLS  3
#define DD    160          // NH + PC
#define HDD   20           // D / TH
#define NND   856          // nodes
#define NPAD  896          // padded to 14*64 for GEMM
#define NE    2896         // edges
#define NCOLS 4352         // 4096 (msg) + 128 (b2) + 128 (root)
#define NCT   68           // 4352 / 64 column tiles
#define CSTR  32           // CSR bucket stride (max in-degree bound)

// k_setup block-range partition
#define SB_CHEB 428                 // 2 nodes / block
#define SB_PAD  (SB_CHEB)           // 1 block: zero hbf pad rows
#define SB_EAT  (SB_PAD + 1)        // 429
#define NEAT    181                 // ceil(2896/16) edge chunks
#define SB_PACK (SB_EAT + NEAT)     // 610
#define NPACK   (2 * NCT * NLAY)    // 1360
#define SB_CSR  (SB_PACK + NPACK)   // 1970
#define NCSR    12
#define SB_TOT  (SB_CSR + NCSR)     // 1982

typedef __bf16 bf16;
typedef __bf16 bf16x8 __attribute__((ext_vector_type(8)));
typedef float  f32x4  __attribute__((ext_vector_type(4)));

__device__ __forceinline__ float geluf(float z) {
    return 0.5f * z * (1.0f + erff(z * 0.70710678118654752f));
}
__device__ __forceinline__ float wred(float v) {
    #pragma unroll
    for (int o = 32; o; o >>= 1) v += __shfl_xor(v, o, 64);
    return v;
}
__device__ __forceinline__ float dinv_path(int n) {
    return (n == 0 || n == LSEQ - 1) ? 1.0f : 0.70710678118654752f;
}

// ================= k_setup: cheb | hbf-pad | ea+t1 | pack | csr =================
__global__ __launch_bounds__(256) void k_setup(
        const float* __restrict__ x, const float* __restrict__ cw,
        const float* __restrict__ cb, bf16* __restrict__ hbf,
        const float* __restrict__ eattr, const float* __restrict__ eew,
        const float* __restrict__ eeb, const float* __restrict__ w1,
        const float* __restrict__ b1, float* __restrict__ t1,
        const float* __restrict__ w2, const float* __restrict__ b2,
        const float* __restrict__ rootw, bf16* __restrict__ bp,
        const int* __restrict__ ei, int* __restrict__ deg, int* __restrict__ csr) {
    __shared__ __align__(16) char sm[64 * 65 * 2];
    int blk = blockIdx.x, tid = threadIdx.x;
    if (blk < SB_CHEB) {
        // --- ChebConv, 2 nodes per block, 5-point stencil (R4/R5-validated) ---
        float (*xs)[5][NNF] = (float (*)[5][NNF])sm;
        int s = tid >> 7, o = tid & 127;
        int n = blk * 2 + s;
        int g = n / LSEQ, i = n - g * LSEQ;
        if (o < 5 * NNF) {
            int k = o / NNF, f = o - k * NNF;
            int p = i - 2 + k; p = p < 0 ? 0 : (p > LSEQ - 1 ? LSEQ - 1 : p);
            xs[s][k][f] = x[(g * LSEQ + p) * NNF + f];
        }
        __syncthreads();
        float di  = dinv_path(i);
        float dm1 = dinv_path(i - 1 < 0 ? 0 : i - 1);
        float dp1 = dinv_path(i + 1 > LSEQ - 1 ? LSEQ - 1 : i + 1);
        float dm2 = dinv_path(i - 2 < 0 ? 0 : i - 2);
        float dp2 = dinv_path(i + 2 > LSEQ - 1 ? LSEQ - 1 : i + 2);
        float wmc = (i > 0)        ? -(dm1 * di) : 0.f;
        float wpc = (i < LSEQ - 1) ? -(dp1 * di) : 0.f;
        float wmm = (i - 1 > 0)        ? -(dm2 * dm1) : 0.f;
        float wpm = -(di * dm1);
        float wmp = -(di * dp1);
        float wpp = (i + 1 < LSEQ - 1) ? -(dp2 * dp1) : 0.f;
        float acc = cb[o];
        #pragma unroll
        for (int f = 0; f < NNF; ++f) {
            float xm2 = xs[s][0][f], xm1 = xs[s][1][f], x0 = xs[s][2][f],
                  xp1 = xs[s][3][f], xp2 = xs[s][4][f];
            float t1c = wmc * xm1 + wpc * xp1;
            float t1m = wmm * xm2 + wpm * x0;
            float t1p = wmp * x0 + wpp * xp2;
            float t2 = 2.f * (wmc * t1m + wpc * t1p) - x0;
            acc += x0 * cw[f * NH + o] + t1c * cw[(NNF + f) * NH + o]
                 + t2 * cw[(2 * NNF + f) * NH + o];
        }
        hbf[n * NH + o] = (bf16)acc;   // layer-0 GEMM A input (no LN on layer 0)
    } else if (blk == SB_PAD) {
        for (int i = tid; i < (NPAD - NND) * NH; i += 256)
            hbf[NND * NH + i] = (bf16)0.f;
    } else if (blk < SB_PACK) {
        // --- fused edge encoder + all-layer t1, 16 edges per block ---
        float (*eas)[EHD] = (float (*)[EHD])sm;
        int base = (blk - SB_EAT) * 16;
        #pragma unroll
        for (int r = 0; r < 2; ++r) {
            int i = tid + r * 256;
            int el = i >> 5, c = i & 31, e = base + el;
            if (e < NE) {
                float acc = eeb[c];
                #pragma unroll
                for (int f = 0; f < NEF; ++f) acc += eattr[e * NEF + f] * eew[f * EHD + c];
                eas[el][c] = acc;
            }
        }
        __syncthreads();
        for (int l = 0; l < NLAY; ++l) {
            #pragma unroll
            for (int r = 0; r < 2; ++r) {
                int i = tid + r * 256;
                int el = i >> 5, c = i & 31, e = base + el;
                if (e < NE) {
                    float acc = b1[l * H3D + c];
                    #pragma unroll
                    for (int j = 0; j < EHD; ++j) acc += eas[el][j] * w1[(l * EHD + j) * H3D + c];
                    t1[((size_t)l * NE + e) * H3D + c] = acc;
                }
            }
        }
    } else if (blk < SB_CSR) {
        // --- pack B tile (R2/R5-validated) ---
        bf16 (*tt)[65] = (bf16 (*)[65])sm;
        int v = blk - SB_PACK;
        int kt = v & 1, rest = v >> 1;
        int ct = rest % NCT, l = rest / NCT;
        int cc = tid & 63, rr = tid >> 6;
        int colbase = ct * 64;
        #pragma unroll
        for (int rep = 0; rep < 16; ++rep) {
            int kk = rep * 4 + rr;
            int k = kt * 64 + kk;
            int col = colbase + cc;
            float val;
            if (col < 4096) {
                int j = col >> 7, o = col & 127;
                val = w2[(size_t)l * 524288 + j * 16384 + k * 128 + o];
            } else if (col < 4224) {
                val = b2[(size_t)l * 16384 + k * 128 + (col - 4096)];
            } else {
                val = rootw[(size_t)l * 16384 + k * 128 + (col - 4224)];
            }
            tt[kk][cc] = (bf16)val;
        }
        __syncthreads();
        #pragma unroll
        for (int rep = 0; rep < 16; ++rep) {
            int c = rep * 4 + rr;
            bp[((size_t)((l * NCT + ct) * 64 + c)) * 128 + kt * 64 + cc] = tt[cc][c];
        }
    } else {
        // --- CSR build: incoming-edge buckets per dst ---
        int e = (blk - SB_CSR) * 256 + tid;
        if (e < NE) {
            int d = ei[NE + e];
            int slot = atomicAdd(&deg[d], 1);
            if (slot < CSTR) csr[d * CSTR + slot] = e;
        }
    }
}

// ================= MFMA GEMM: HW[896 x 4352](bf16) = hbf @ Bpack (R2-validated) =================
__global__ __launch_bounds__(256) void k_gemm(const bf16* __restrict__ hbf,
                                              const bf16* __restrict__ bp,
                                              bf16* __restrict__ HW) {
    int lane = threadIdx.x & 63, wv = threadIdx.x >> 6;
    int m0 = blockIdx.y * 64 + wv * 16;
    int ct = blockIdx.x;
    int r = lane & 15, q = lane >> 4;
    const bf16* Arow = hbf + (size_t)(m0 + r) * NH;
    const bf16* Bb = bp + ((size_t)ct * 64 + r) * NH;
    f32x4 a0 = {0.f,0.f,0.f,0.f}, a1 = a0, a2 = a0, a3 = a0;
    int q8 = q * 8;
    #pragma unroll
    for (int ks = 0; ks < 4; ++ks) {
        int kb = ks * 32 + q8;
        bf16x8 av = *(const bf16x8*)(Arow + kb);
        bf16x8 b0 = *(const bf16x8*)(Bb + 0 * 16 * NH + kb);
        bf16x8 b1 = *(const bf16x8*)(Bb + 1 * 16 * NH + kb);
        bf16x8 b2 = *(const bf16x8*)(Bb + 2 * 16 * NH + kb);
        bf16x8 b3 = *(const bf16x8*)(Bb + 3 * 16 * NH + kb);
        a0 = __builtin_amdgcn_mfma_f32_16x16x32_bf16(av, b0, a0, 0, 0, 0);
        a1 = __builtin_amdgcn_mfma_f32_16x16x32_bf16(av, b1, a1, 0, 0, 0);
        a2 = __builtin_amdgcn_mfma_f32_16x16x32_bf16(av, b2, a2, 0, 0, 0);
        a3 = __builtin_amdgcn_mfma_f32_16x16x32_bf16(av, b3, a3, 0, 0, 0);
    }
    int cb = ct * 64;
    #pragma unroll
    for (int reg = 0; reg < 4; ++reg) {
        bf16* Crow = HW + (size_t)(m0 + q * 4 + reg) * NCOLS + cb;
        Crow[0 * 16 + r] = (bf16)a0[reg];
        Crow[1 * 16 + r] = (bf16)a1[reg];
        Crow[2 * 16 + r] = (bf16)a2[reg];
        Crow[3 * 16 + r] = (bf16)a3[reg];
    }
}

// ================= CSR gather: full aggregation for dst d + fused next-layer prep =================
__global__ __launch_bounds__(128) void k_edgeg(const int* __restrict__ ei,
                                               const float* __restrict__ t1l,
                                               const bf16* __restrict__ HW,
                                               float* __restrict__ h,
                                               bf16* __restrict__ hbf,
                                               float* __restrict__ tbuf,
                                               const float* __restrict__ lng,
                                               const float* __restrict__ lnb,
                                               const float* __restrict__ cbias,
                                               const int* __restrict__ deg,
                                               const int* __restrict__ csr,
                                               int l) {
    __shared__ float ts[CSTR * H3D];
    __shared__ int elist[CSTR], slist[CSTR];
    __shared__ float red[4];
    int d = blockIdx.x, o = threadIdx.x;
    int dg = deg[d]; if (dg > CSTR) dg = CSTR;
    if (o < dg) {
        int e = csr[d * CSTR + o];
        elist[o] = e;
        slist[o] = ei[e];
    }
    __syncthreads();
    for (int i = o; i < dg * H3D; i += 128) ts[i] = t1l[(size_t)elist[i >> 5] * H3D + (i & 31)];
    __syncthreads();
    float acc = cbias[l * NH + o];
    if (l > 0) acc += h[d * NH + o];
    acc += (float)HW[(size_t)d * NCOLS + 4224 + o];         // root part
    for (int k = 0; k < dg; ++k) {
        const bf16* row = HW + (size_t)slist[k] * NCOLS;
        float a2 = (float)row[4096 + o];                    // b2 part
        #pragma unroll
        for (int j = 0; j < H3D; ++j) a2 += ts[k * H3D + j] * (float)row[j * NH + o];
        acc += a2;
    }
    h[d * NH + o] = acc;        // in-place: only this block touches row d
    // LN over 128 (2 waves) + gelu -> next-layer GEMM input (or final tbuf)
    int wv = o >> 6;
    float s = wred(acc);
    if ((o & 63) == 0) red[wv] = s;
    __syncthreads();
    float m = (red[0] + red[1]) * (1.f / NH);
    float dv = acc - m;
    s = wred(dv * dv);
    if ((o & 63) == 0) red[2 + wv] = s;
    __syncthreads();
    float var = (red[2] + red[3]) * (1.f / NH);
    float rs = rsqrtf(var + 1e-5f);
    if (l < NLAY - 1) {
        int ln = l + 1;
        float z = geluf(dv * rs * lng[ln * NH + o] + lnb[ln * NH + o]);
        hbf[d * NH + o] = (bf16)z;
    } else {
        float z = geluf(dv * rs * lng[o] + lnb[o]);         // layer-0 norm reused
        tbuf[(size_t)d * DD + o] = z;
        if (o < PCD) {
            int qq = d % LSEQ;
            float twoi = (float)(o & ~1);
            float ang = (float)qq * expf(-twoi * 0.28782313662425572f); // ln(1e4)/32
            tbuf[(size_t)d * DD + NH + o] = (o & 1) ? cosf(ang) : sinf(ang);
        }
    }
}

// ================= generic small GEMM (R2-validated, used for qkv) =================
__global__ void k_mm(const float* __restrict__ A, const float* __restrict__ B,
                     const float* __restrict__ bias, float* __restrict__ C,
                     int M, int K, int Ncols, int act) {
    int col = blockIdx.x * 64 + threadIdx.x;
    int row = blockIdx.y * 4 + threadIdx.y;
    if (row >= M || col >= Ncols) return;
    float acc = bias[col];
    const float* a = A + (size_t)row * K;
    const float* b = B + col;
    #pragma unroll 8
    for (int k = 0; k < K; ++k) acc += a[k] * b[(size_t)k * Ncols];
    if (act) acc = fmaxf(acc, 0.f);
    C[(size_t)row * Ncols + col] = acc;
}

// ================= attention (R3-validated): online softmax, float4, 1 wave/block =================
#define UPD4(ac, V) { ac.x = ac.x * corr + p * V.x; ac.y = ac.y * corr + p * V.y; \
                      ac.z = ac.z * corr + p * V.z; ac.w = ac.w * corr + p * V.w; }
__global__ __launch_bounds__(64) void k_attn(const float* __restrict__ qkv,
                                             float* __restrict__ aout) {
    __shared__ float4 Ks4[LSEQ * 5], Vs4[LSEQ * 5];
    int bh = blockIdx.x;
    int b = bh >> 3, hh = bh & 7;
    int tid = threadIdx.x;
    for (int i = tid; i < LSEQ * 5; i += 64) {
        int kq = i / 5, c4 = i - kq * 5;
        const float* rowp = qkv + (size_t)(b * LSEQ + kq) * (3 * DD) + hh * HDD;
        Ks4[i] = ((const float4*)(rowp + DD))[c4];
        Vs4[i] = ((const float4*)(rowp + 2 * DD))[c4];
    }
    __syncthreads();
    int q = blockIdx.y * 64 + tid;
    if (q >= LSEQ) return;
    const float4* qp = (const float4*)(qkv + (size_t)(b * LSEQ + q) * (3 * DD) + hh * HDD);
    float4 q0 = qp[0], q1 = qp[1], q2 = qp[2], q3 = qp[3], q4 = qp[4];
    const float scale = 0.22360679774997896f;
    float mx = -3.0e38f, sum = 0.f;
    float4 z = {0.f, 0.f, 0.f, 0.f};
    float4 ac0 = z, ac1 = z, ac2 = z, ac3 = z, ac4 = z;
    for (int k = 0; k < LSEQ; ++k) {
        const float4* kp = Ks4 + k * 5;
        float4 K0 = kp[0], K1 = kp[1], K2 = kp[2], K3 = kp[3], K4 = kp[4];
        float a0 = q0.x * K0.x + q0.y * K0.y + q0.z * K0.z + q0.w * K0.w;
        float a1 = q1.x * K1.x + q1.y * K1.y + q1.z * K1.z + q1.w * K1.w;
        float a2 = q2.x * K2.x + q2.y * K2.y + q2.z * K2.z + q2.w * K2.w;
        float a3 = q3.x * K3.x + q3.y * K3.y + q3.z * K3.z + q3.w * K3.w;
        float a4 = q4.x * K4.x + q4.y * K4.y + q4.z * K4.z + q4.w * K4.w;
        float s = (((a0 + a1) + (a2 + a3)) + a4) * scale;
        float mn = fmaxf(mx, s);
        float corr = __expf(mx - mn);
        float p = __expf(s - mn);
        mx = mn;
        sum = sum * corr + p;
        const float4* vp = Vs4 + k * 5;
        float4 V0 = vp[0], V1 = vp[1], V2 = vp[2], V3 = vp[3], V4 = vp[4];
        UPD4(ac0, V0); UPD4(ac1, V1); UPD4(ac2, V2); UPD4(ac3, V3); UPD4(ac4, V4);
    }
    float inv = 1.f / sum;
    float4* op = (float4*)(aout + (size_t)(b * LSEQ + q) * DD + hh * HDD);
    float4 o0 = {ac0.x * inv, ac0.y * inv, ac0.z * inv, ac0.w * inv};
    float4 o1 = {ac1.x * inv, ac1.y * inv, ac1.z * inv, ac1.w * inv};
    float4 o2 = {ac2.x * inv, ac2.y * inv, ac2.z * inv, ac2.w * inv};
    float4 o3 = {ac3.x * inv, ac3.y * inv, ac3.z * inv, ac3.w * inv};
    float4 o4 = {ac4.x * inv, ac4.y * inv, ac4.z * inv, ac4.w * inv};
    op[0] = o0; op[1] = o1; op[2] = o2; op[3] = o3; op[4] = o4;
}

// ================= transformer tail: proj+LN1+FFN1+FFN2+LN2 (+final lin), per row =================
__global__ __launch_bounds__(256) void k_tail(const float* __restrict__ abuf,
                                              float* __restrict__ tbuf,
                                              const float* __restrict__ aow,
                                              const float* __restrict__ aob,
                                              const float* __restrict__ g1,
                                              const float* __restrict__ b1,
                                              const float* __restrict__ fw1,
                                              const float* __restrict__ fb1,
                                              const float* __restrict__ fw2,
                                              const float* __restrict__ fb2,
                                              const float* __restrict__ g2,
                                              const float* __restrict__ b2,
                                              const float* __restrict__ lw,
                                              const float* __restrict__ lb,
                                              float* __restrict__ outp) {
    __shared__ float arow[DD], ns1[DD], f1s[FFD], ns2[DD], red[8];
    int r = blockIdx.x, tid = threadIdx.x;
    if (tid < DD) arow[tid] = abuf[(size_t)r * DD + tid];
    __syncthreads();
    float v = 0.f;
    if (tid < DD) {
        v = aob[tid];
        #pragma unroll 4
        for (int k = 0; k < DD; ++k) v += arow[k] * aow[(size_t)k * DD + tid];
        v += tbuf[(size_t)r * DD + tid];
    }
    float s = wred(v);
    if ((tid & 63) == 0) red[tid >> 6] = s;
    __syncthreads();
    float m = (red[0] + red[1] + red[2] + red[3]) * (1.f / DD);
    float dv = (tid < DD) ? v - m : 0.f;
    s = wred(dv * dv);
    if ((tid & 63) == 0) red[4 + (tid >> 6)] = s;
    __syncthreads();
    float var = (red[4] + red[5] + red[6] + red[7]) * (1.f / DD);
    float rs = rsqrtf(var + 1e-5f);
    if (tid < DD) ns1[tid] = dv * rs * g1[tid] + b1[tid];
    __syncthreads();
    // FFN1 (relu), 256 outputs
    float f = fb1[tid];
    #pragma unroll 4
    for (int k = 0; k < DD; ++k) f += ns1[k] * fw1[(size_t)k * FFD + tid];
    f1s[tid] = fmaxf(f, 0.f);
    __syncthreads();
    float v2 = 0.f;
    if (tid < DD) {
        v2 = fb2[tid];
        #pragma unroll 4
        for (int k = 0; k < FFD; ++k) v2 += f1s[k] * fw2[(size_t)k * DD + tid];
        v2 += ns1[tid];
    }
    s = wred(v2);
    if ((tid & 63) == 0) red[tid >> 6] = s;
    __syncthreads();
    m = (red[0] + red[1] + red[2] + red[3]) * (1.f / DD);
    dv = (tid < DD) ? v2 - m : 0.f;
    s = wred(dv * dv);
    if ((tid & 63) == 0) red[4 + (tid >> 6)] = s;
    __syncthreads();
    var = (red[4] + red[5] + red[6] + red[7]) * (1.f / DD);
    rs = rsqrtf(var + 1e-5f);
    if (tid < DD) {
        float nv = dv * rs * g2[tid] + b2[tid];
        tbuf[(size_t)r * DD + tid] = nv;
        ns2[tid] = nv;
    }
    if (outp) {
        __syncthreads();
        if (tid < NCLS) {
            float a = lb[tid];
            for (int k = 0; k < DD; ++k) a += ns2[k] * lw[k * NCLS + tid];
            outp[r * NCLS + tid] = a;
        }
    }
}

extern "C" void kernel_launch(void* const* d_in, const int* in_sizes, int n_in,
                              void* d_out, int out_size, void* d_ws, size_t ws_size,
                              hipStream_t stream) {
    (void)in_sizes; (void)n_in; (void)out_size; (void)ws_size;
    const float* x      = (const float*)d_in[0];
    const float* eattr  = (const float*)d_in[1];
    const float* cheb_w = (const float*)d_in[2];
    const float* cheb_b = (const float*)d_in[3];
    const float* ee_w   = (const float*)d_in[4];
    const float* ee_b   = (const float*)d_in[5];
    const float* mlp_w1 = (const float*)d_in[6];
    const float* mlp_b1 = (const float*)d_in[7];
    const float* mlp_w2 = (const float*)d_in[8];
    const float* mlp_b2 = (const float*)d_in[9];
    const float* root_w = (const float*)d_in[10];
    const float* conv_b = (const float*)d_in[11];
    const float* ln_g   = (const float*)d_in[12];
    const float* ln_b   = (const float*)d_in[13];
    const float* ain_w  = (const float*)d_in[14];
    const float* ain_b  = (const float*)d_in[15];
    const float* aow    = (const float*)d_in[16];
    const float* aob    = (const float*)d_in[17];
    const float* ffw1   = (const float*)d_in[18];
    const float* ffb1   = (const float*)d_in[19];
    const float* ffw2   = (const float*)d_in[20];
    const float* ffb2   = (const float*)d_in[21];
    const float* t1g    = (const float*)d_in[22];
    const float* t1b    = (const float*)d_in[23];
    const float* t2g    = (const float*)d_in[24];
    const float* t2b    = (const float*)d_in[25];
    const float* lin_w  = (const float*)d_in[26];
    const float* lin_b  = (const float*)d_in[27];
    const int* ei       = (const int*)d_in[29];

    char* w = (char*)d_ws;
    size_t off = 0;
    auto alloc = [&](size_t bytes) -> void* {
        void* p = w + off;
        off += (bytes + 255) & ~(size_t)255;
        return p;
    };
    bf16*  bpack = (bf16*)alloc((size_t)NLAY * NCT * 64 * NH * 2);   // 11.1 MB
    float* t1all = (float*)alloc((size_t)NLAY * NE * H3D * 4);       // 3.7 MB
    float* h     = (float*)alloc((size_t)NND * NH * 4);
    bf16*  hbf   = (bf16*)alloc((size_t)NPAD * NH * 2);
    bf16*  HW    = (bf16*)alloc((size_t)NPAD * NCOLS * 2);           // 7.8 MB
    float* tbuf  = (float*)alloc((size_t)NND * DD * 4);
    float* qkv   = (float*)alloc((size_t)NND * 3 * DD * 4);
    float* abuf  = (float*)alloc((size_t)NND * DD * 4);
    int*   deg   = (int*)alloc((size_t)NND * 4);
    int*   csr   = (int*)alloc((size_t)NND * CSTR * 4);

    hipMemsetAsync(deg, 0, (size_t)NND * 4, stream);

    // --- one setup dispatch: cheb(+hbf0), hbf pad, ea+t1, pack, CSR ---
    k_setup<<<SB_TOT, 256, 0, stream>>>(x, cheb_w, cheb_b, hbf,
                                        eattr, ee_w, ee_b, mlp_w1, mlp_b1, t1all,
                                        mlp_w2, mlp_b2, root_w, bpack, ei, deg, csr);

    // --- 10 NNConv layers: GEMM + CSR-gather(+fused prep/final) ---
    for (int l = 0; l < NLAY; ++l) {
        k_gemm<<<dim3(NCT, 14), 256, 0, stream>>>(hbf, bpack + (size_t)l * NCT * 64 * NH, HW);
        k_edgeg<<<NND, 128, 0, stream>>>(ei, t1all + (size_t)l * NE * H3D, HW, h, hbf, tbuf,
                                         ln_g, ln_b, conv_b, deg, csr, l);
    }

    // --- transformer encoder: qkv + attn + fused tail per layer ---
    for (int tl = 0; tl < TLAY; ++tl) {
        k_mm<<<dim3(8, 214), dim3(64, 4), 0, stream>>>(tbuf, ain_w + (size_t)tl * DD * 3 * DD,
                                                       ain_b + (size_t)tl * 3 * DD, qkv,
                                                       NND, DD, 3 * DD, 0);
        k_attn<<<dim3(BSZ * THD, 2), 64, 0, stream>>>(qkv, abuf);
        int last = (tl == TLAY - 1);
        k_tail<<<NND, 256, 0, stream>>>(abuf, tbuf,
                                        aow + (size_t)tl * DD * DD, aob + (size_t)tl * DD,
                                        t1g + (size_t)tl * DD, t1b + (size_t)tl * DD,
                                        ffw1 + (size_t)tl * DD * FFD, ffb1 + (size_t)tl * FFD,
                                        ffw2 + (size_t)tl * FFD * DD, ffb2 + (size_t)tl * DD,
                                        t2g + (size_t)tl * DD, t2b + (size_t)tl * DD,
                                        last ? lin_w : nullptr, last ? lin_b : nullptr,
                                        last ? (float*)d_out : nullptr);
    }
}

// Round 8
// 562.325 us; speedup vs baseline: 4.0016x; 1.1549x over previous
//
#include <hip/hip_runtime.h>
#include <hip/hip_bf16.h>
#include <math.h>

// ---------------- problem constants ----------------
#define BSZ   8
#define LSEQ  107
#define NNF   17
#define NEF   9
#define NH    128
#define EHD   32
#define H3D   32
#define NLAY  10
#define PCD   32
#define TLAY  3
#define THD   8
#define FFD   256
#define NCLS  3
#define DD    160          // NH + PC
#define HDD   20           // D / TH
#define NND   856          // nodes
#define NPAD  896          // padded to 14*64 for GEMM
#define NE    2896         // edges
#define NCOLS 4352         // 4096 (msg) + 128 (b2) + 128 (root)
#define NCT   68           // 4352 / 64 column tiles
#define CSTR  32           // CSR bucket stride (max in-degree bound)
#define QKVP  512          // padded qkv width
#define PRJP  192          // padded proj/ffn2 width

// k_setup block-range partition
#define SB_CHEB 428                 // 2 nodes / block
#define SB_PAD  (SB_CHEB)           // 1 block: zero hbf pad rows
#define SB_EAT  (SB_PAD + 1)        // 429
#define NEAT    181                 // ceil(2896/16) edge chunks
#define SB_PACK (SB_EAT + NEAT)     // 610
#define NPACK   (2 * NCT * NLAY)    // 1360
#define SB_CSR  (SB_PACK + NPACK)   // 1970
#define NCSR    12
#define SB_TPK  (SB_CSR + NCSR)     // 1982: transformer weight pack
#define NTPK    54                  // 3 layers x (8 qkv + 3 proj + 4 ffn1 + 3 ffn2)
#define SB_BIAS (SB_TPK + NTPK)     // 2036: padded bias pack
#define SB_TOT  (SB_BIAS + 1)       // 2037

typedef __bf16 bf16;
typedef __bf16 bf16x8 __attribute__((ext_vector_type(8)));
typedef float  f32x4  __attribute__((ext_vector_type(4)));

__device__ __forceinline__ float geluf(float z) {
    return 0.5f * z * (1.0f + erff(z * 0.70710678118654752f));
}
__device__ __forceinline__ float wred(float v) {
    #pragma unroll
    for (int o = 32; o; o >>= 1) v += __shfl_xor(v, o, 64);
    return v;
}
__device__ __forceinline__ float dinv_path(int n) {
    return (n == 0 || n == LSEQ - 1) ? 1.0f : 0.70710678118654752f;
}

// ================= k_setup: cheb | hbf-pad | ea+t1 | pack | csr | tpack | bias =================
__global__ __launch_bounds__(256) void k_setup(
        const float* __restrict__ x, const float* __restrict__ cw,
        const float* __restrict__ cb, bf16* __restrict__ hbf,
        const float* __restrict__ eattr, const float* __restrict__ eew,
        const float* __restrict__ eeb, const float* __restrict__ w1,
        const float* __restrict__ b1, float* __restrict__ t1,
        const float* __restrict__ w2, const float* __restrict__ b2,
        const float* __restrict__ rootw, bf16* __restrict__ bp,
        const int* __restrict__ ei, int* __restrict__ deg, int* __restrict__ csr,
        const float* __restrict__ ain_w, const float* __restrict__ aow,
        const float* __restrict__ ffw1, const float* __restrict__ ffw2,
        const float* __restrict__ ain_b, const float* __restrict__ aob,
        const float* __restrict__ ffb1, const float* __restrict__ ffb2,
        bf16* __restrict__ bqkv, bf16* __restrict__ bproj,
        bf16* __restrict__ bff1, bf16* __restrict__ bff2,
        float* __restrict__ tb_bias) {
    __shared__ __align__(16) char sm[64 * 65 * 2];
    int blk = blockIdx.x, tid = threadIdx.x;
    if (blk < SB_CHEB) {
        float (*xs)[5][NNF] = (float (*)[5][NNF])sm;
        int s = tid >> 7, o = tid & 127;
        int n = blk * 2 + s;
        int g = n / LSEQ, i = n - g * LSEQ;
        if (o < 5 * NNF) {
            int k = o / NNF, f = o - k * NNF;
            int p = i - 2 + k; p = p < 0 ? 0 : (p > LSEQ - 1 ? LSEQ - 1 : p);
            xs[s][k][f] = x[(g * LSEQ + p) * NNF + f];
        }
        __syncthreads();
        float di  = dinv_path(i);
        float dm1 = dinv_path(i - 1 < 0 ? 0 : i - 1);
        float dp1 = dinv_path(i + 1 > LSEQ - 1 ? LSEQ - 1 : i + 1);
        float dm2 = dinv_path(i - 2 < 0 ? 0 : i - 2);
        float dp2 = dinv_path(i + 2 > LSEQ - 1 ? LSEQ - 1 : i + 2);
        float wmc = (i > 0)        ? -(dm1 * di) : 0.f;
        float wpc = (i < LSEQ - 1) ? -(dp1 * di) : 0.f;
        float wmm = (i - 1 > 0)        ? -(dm2 * dm1) : 0.f;
        float wpm = -(di * dm1);
        float wmp = -(di * dp1);
        float wpp = (i + 1 < LSEQ - 1) ? -(dp2 * dp1) : 0.f;
        float acc = cb[o];
        #pragma unroll
        for (int f = 0; f < NNF; ++f) {
            float xm2 = xs[s][0][f], xm1 = xs[s][1][f], x0 = xs[s][2][f],
                  xp1 = xs[s][3][f], xp2 = xs[s][4][f];
            float t1c = wmc * xm1 + wpc * xp1;
            float t1m = wmm * xm2 + wpm * x0;
            float t1p = wmp * x0 + wpp * xp2;
            float t2 = 2.f * (wmc * t1m + wpc * t1p) - x0;
            acc += x0 * cw[f * NH + o] + t1c * cw[(NNF + f) * NH + o]
                 + t2 * cw[(2 * NNF + f) * NH + o];
        }
        hbf[n * NH + o] = (bf16)acc;
    } else if (blk == SB_PAD) {
        for (int i = tid; i < (NPAD - NND) * NH; i += 256)
            hbf[NND * NH + i] = (bf16)0.f;
    } else if (blk < SB_PACK) {
        float (*eas)[EHD] = (float (*)[EHD])sm;
        int base = (blk - SB_EAT) * 16;
        #pragma unroll
        for (int r = 0; r < 2; ++r) {
            int i = tid + r * 256;
            int el = i >> 5, c = i & 31, e = base + el;
            if (e < NE) {
                float acc = eeb[c];
                #pragma unroll
                for (int f = 0; f < NEF; ++f) acc += eattr[e * NEF + f] * eew[f * EHD + c];
                eas[el][c] = acc;
            }
        }
        __syncthreads();
        for (int l = 0; l < NLAY; ++l) {
            #pragma unroll
            for (int r = 0; r < 2; ++r) {
                int i = tid + r * 256;
                int el = i >> 5, c = i & 31, e = base + el;
                if (e < NE) {
                    float acc = b1[l * H3D + c];
                    #pragma unroll
                    for (int j = 0; j < EHD; ++j) acc += eas[el][j] * w1[(l * EHD + j) * H3D + c];
                    t1[((size_t)l * NE + e) * H3D + c] = acc;
                }
            }
        }
    } else if (blk < SB_CSR) {
        bf16 (*tt)[65] = (bf16 (*)[65])sm;
        int v = blk - SB_PACK;
        int kt = v & 1, rest = v >> 1;
        int ct = rest % NCT, l = rest / NCT;
        int cc = tid & 63, rr = tid >> 6;
        int colbase = ct * 64;
        #pragma unroll
        for (int rep = 0; rep < 16; ++rep) {
            int kk = rep * 4 + rr;
            int k = kt * 64 + kk;
            int col = colbase + cc;
            float val;
            if (col < 4096) {
                int j = col >> 7, o = col & 127;
                val = w2[(size_t)l * 524288 + j * 16384 + k * 128 + o];
            } else if (col < 4224) {
                val = b2[(size_t)l * 16384 + k * 128 + (col - 4096)];
            } else {
                val = rootw[(size_t)l * 16384 + k * 128 + (col - 4224)];
            }
            tt[kk][cc] = (bf16)val;
        }
        __syncthreads();
        #pragma unroll
        for (int rep = 0; rep < 16; ++rep) {
            int c = rep * 4 + rr;
            bp[((size_t)((l * NCT + ct) * 64 + c)) * 128 + kt * 64 + cc] = tt[cc][c];
        }
    } else if (blk < SB_TPK) {
        int e = (blk - SB_CSR) * 256 + tid;
        if (e < NE) {
            int d = ei[NE + e];
            int slot = atomicAdd(&deg[d], 1);
            if (slot < CSTR) csr[d * CSTR + slot] = e;
        }
    } else if (blk < SB_BIAS) {
        // --- transformer weight pack: dst[col][k] bf16, zero-padded cols ---
        int v = blk - SB_TPK;
        int tl = v / 18, t = v % 18;
        const float* src; bf16* dst; int Kd, srcN, ct;
        if (t < 8)       { ct = t;      src = ain_w + (size_t)tl * DD * 3 * DD; srcN = 3 * DD; Kd = DD;  dst = bqkv  + ((size_t)tl * QKVP + ct * 64) * DD; }
        else if (t < 11) { ct = t - 8;  src = aow   + (size_t)tl * DD * DD;     srcN = DD;     Kd = DD;  dst = bproj + ((size_t)tl * PRJP + ct * 64) * DD; }
        else if (t < 15) { ct = t - 11; src = ffw1  + (size_t)tl * DD * FFD;    srcN = FFD;    Kd = DD;  dst = bff1  + ((size_t)tl * FFD + ct * 64) * DD; }
        else             { ct = t - 15; src = ffw2  + (size_t)tl * FFD * DD;    srcN = DD;     Kd = FFD; dst = bff2  + ((size_t)tl * PRJP + ct * 64) * FFD; }
        int cc = tid & 63, kg = tid >> 6;
        int col = ct * 64 + cc;
        for (int k = kg; k < Kd; k += 4) {
            float val = (col < srcN) ? src[(size_t)k * srcN + col] : 0.f;
            dst[(size_t)cc * Kd + k] = (bf16)val;
        }
    } else {
        // --- padded bias pack: [tl][512 qkv | 192 proj | 256 ffn1 | 192 ffn2] ---
        for (int i = tid; i < 3 * 1152; i += 256) {
            int tl = i / 1152, r = i % 1152;
            float val;
            if (r < 512)      { val = (r < 480) ? ain_b[tl * 480 + r] : 0.f; }
            else if (r < 704) { int c = r - 512; val = (c < 160) ? aob[tl * 160 + c] : 0.f; }
            else if (r < 960) { int c = r - 704; val = ffb1[tl * 256 + c]; }
            else              { int c = r - 960; val = (c < 160) ? ffb2[tl * 160 + c] : 0.f; }
            tb_bias[i] = val;
        }
    }
}

// ================= NNConv MFMA GEMM (R2-validated) =================
__global__ __launch_bounds__(256) void k_gemm(const bf16* __restrict__ hbf,
                                              const bf16* __restrict__ bp,
                                              bf16* __restrict__ HW) {
    int lane = threadIdx.x & 63, wv = threadIdx.x >> 6;
    int m0 = blockIdx.y * 64 + wv * 16;
    int ct = blockIdx.x;
    int r = lane & 15, q = lane >> 4;
    const bf16* Arow = hbf + (size_t)(m0 + r) * NH;
    const bf16* Bb = bp + ((size_t)ct * 64 + r) * NH;
    f32x4 a0 = {0.f,0.f,0.f,0.f}, a1 = a0, a2 = a0, a3 = a0;
    int q8 = q * 8;
    #pragma unroll
    for (int ks = 0; ks < 4; ++ks) {
        int kb = ks * 32 + q8;
        bf16x8 av = *(const bf16x8*)(Arow + kb);
        bf16x8 b0 = *(const bf16x8*)(Bb + 0 * 16 * NH + kb);
        bf16x8 b1 = *(const bf16x8*)(Bb + 1 * 16 * NH + kb);
        bf16x8 b2 = *(const bf16x8*)(Bb + 2 * 16 * NH + kb);
        bf16x8 b3 = *(const bf16x8*)(Bb + 3 * 16 * NH + kb);
        a0 = __builtin_amdgcn_mfma_f32_16x16x32_bf16(av, b0, a0, 0, 0, 0);
        a1 = __builtin_amdgcn_mfma_f32_16x16x32_bf16(av, b1, a1, 0, 0, 0);
        a2 = __builtin_amdgcn_mfma_f32_16x16x32_bf16(av, b2, a2, 0, 0, 0);
        a3 = __builtin_amdgcn_mfma_f32_16x16x32_bf16(av, b3, a3, 0, 0, 0);
    }
    int cb = ct * 64;
    #pragma unroll
    for (int reg = 0; reg < 4; ++reg) {
        bf16* Crow = HW + (size_t)(m0 + q * 4 + reg) * NCOLS + cb;
        Crow[0 * 16 + r] = (bf16)a0[reg];
        Crow[1 * 16 + r] = (bf16)a1[reg];
        Crow[2 * 16 + r] = (bf16)a2[reg];
        Crow[3 * 16 + r] = (bf16)a3[reg];
    }
}

// ================= generic MFMA GEMM: C[M x PW] = cvt_bf16(A[M x K]) @ Bpack + biasP =================
__global__ __launch_bounds__(256) void k_gmm(const float* __restrict__ A,
                                             const bf16* __restrict__ bp,
                                             const float* __restrict__ biasP,
                                             float* __restrict__ C,
                                             int ksteps, int K, int PW, int act) {
    int lane = threadIdx.x & 63, wv = threadIdx.x >> 6;
    int m0 = blockIdx.y * 64 + wv * 16;
    int ct = blockIdx.x;
    int r = lane & 15, q = lane >> 4, q8 = q * 8;
    const float* Arow = A + (size_t)(m0 + r) * K;
    const bf16* Bb = bp + ((size_t)ct * 64 + r) * K;
    f32x4 a0 = {0.f,0.f,0.f,0.f}, a1 = a0, a2 = a0, a3 = a0;
    for (int ks = 0; ks < ksteps; ++ks) {
        int kb = ks * 32 + q8;
        float4 f0 = *(const float4*)(Arow + kb);
        float4 f1 = *(const float4*)(Arow + kb + 4);
        bf16x8 av;
        av[0] = (bf16)f0.x; av[1] = (bf16)f0.y; av[2] = (bf16)f0.z; av[3] = (bf16)f0.w;
        av[4] = (bf16)f1.x; av[5] = (bf16)f1.y; av[6] = (bf16)f1.z; av[7] = (bf16)f1.w;
        bf16x8 b0 = *(const bf16x8*)(Bb + 0 * 16 * K + kb);
        bf16x8 b1 = *(const bf16x8*)(Bb + 1 * 16 * K + kb);
        bf16x8 b2 = *(const bf16x8*)(Bb + 2 * 16 * K + kb);
        bf16x8 b3 = *(const bf16x8*)(Bb + 3 * 16 * K + kb);
        a0 = __builtin_amdgcn_mfma_f32_16x16x32_bf16(av, b0, a0, 0, 0, 0);
        a1 = __builtin_amdgcn_mfma_f32_16x16x32_bf16(av, b1, a1, 0, 0, 0);
        a2 = __builtin_amdgcn_mfma_f32_16x16x32_bf16(av, b2, a2, 0, 0, 0);
        a3 = __builtin_amdgcn_mfma_f32_16x16x32_bf16(av, b3, a3, 0, 0, 0);
    }
    int cb = ct * 64;
    #pragma unroll
    for (int reg = 0; reg < 4; ++reg) {
        float* Crow = C + (size_t)(m0 + q * 4 + reg) * PW + cb;
        float v0 = a0[reg] + biasP[cb + 0 * 16 + r];
        float v1 = a1[reg] + biasP[cb + 1 * 16 + r];
        float v2 = a2[reg] + biasP[cb + 2 * 16 + r];
        float v3 = a3[reg] + biasP[cb + 3 * 16 + r];
        if (act) { v0 = fmaxf(v0, 0.f); v1 = fmaxf(v1, 0.f); v2 = fmaxf(v2, 0.f); v3 = fmaxf(v3, 0.f); }
        Crow[0 * 16 + r] = v0;
        Crow[1 * 16 + r] = v1;
        Crow[2 * 16 + r] = v2;
        Crow[3 * 16 + r] = v3;
    }
}

// ================= CSR gather + fused next-layer prep (R7-validated) =================
__global__ __launch_bounds__(128) void k_edgeg(const int* __restrict__ ei,
                                               const float* __restrict__ t1l,
                                               const bf16* __restrict__ HW,
                                               float* __restrict__ h,
                                               bf16* __restrict__ hbf,
                                               float* __restrict__ tbuf,
                                               const float* __restrict__ lng,
                                               const float* __restrict__ lnb,
                                               const float* __restrict__ cbias,
                                               const int* __restrict__ deg,
                                               const int* __restrict__ csr,
                                               int l) {
    __shared__ float ts[CSTR * H3D];
    __shared__ int elist[CSTR], slist[CSTR];
    __shared__ float red[4];
    int d = blockIdx.x, o = threadIdx.x;
    int dg = deg[d]; if (dg > CSTR) dg = CSTR;
    if (o < dg) {
        int e = csr[d * CSTR + o];
        elist[o] = e;
        slist[o] = ei[e];
    }
    __syncthreads();
    for (int i = o; i < dg * H3D; i += 128) ts[i] = t1l[(size_t)elist[i >> 5] * H3D + (i & 31)];
    __syncthreads();
    float acc = cbias[l * NH + o];
    if (l > 0) acc += h[d * NH + o];
    acc += (float)HW[(size_t)d * NCOLS + 4224 + o];
    for (int k = 0; k < dg; ++k) {
        const bf16* row = HW + (size_t)slist[k] * NCOLS;
        float a2 = (float)row[4096 + o];
        #pragma unroll
        for (int j = 0; j < H3D; ++j) a2 += ts[k * H3D + j] * (float)row[j * NH + o];
        acc += a2;
    }
    h[d * NH + o] = acc;
    int wv = o >> 6;
    float s = wred(acc);
    if ((o & 63) == 0) red[wv] = s;
    __syncthreads();
    float m = (red[0] + red[1]) * (1.f / NH);
    float dv = acc - m;
    s = wred(dv * dv);
    if ((o & 63) == 0) red[2 + wv] = s;
    __syncthreads();
    float var = (red[2] + red[3]) * (1.f / NH);
    float rs = rsqrtf(var + 1e-5f);
    if (l < NLAY - 1) {
        int ln = l + 1;
        float z = geluf(dv * rs * lng[ln * NH + o] + lnb[ln * NH + o]);
        hbf[d * NH + o] = (bf16)z;
    } else {
        float z = geluf(dv * rs * lng[o] + lnb[o]);
        tbuf[(size_t)d * DD + o] = z;
        if (o < PCD) {
            int qq = d % LSEQ;
            float twoi = (float)(o & ~1);
            float ang = (float)qq * expf(-twoi * 0.28782313662425572f);
            tbuf[(size_t)d * DD + NH + o] = (o & 1) ? cosf(ang) : sinf(ang);
        }
    }
}

// ================= attention (R3-validated), qkv row stride QKVP =================
#define UPD4(ac, V) { ac.x = ac.x * corr + p * V.x; ac.y = ac.y * corr + p * V.y; \
                      ac.z = ac.z * corr + p * V.z; ac.w = ac.w * corr + p * V.w; }
__global__ __launch_bounds__(64) void k_attn(const float* __restrict__ qkv,
                                             float* __restrict__ aout) {
    __shared__ float4 Ks4[LSEQ * 5], Vs4[LSEQ * 5];
    int bh = blockIdx.x;
    int b = bh >> 3, hh = bh & 7;
    int tid = threadIdx.x;
    for (int i = tid; i < LSEQ * 5; i += 64) {
        int kq = i / 5, c4 = i - kq * 5;
        const float* rowp = qkv + (size_t)(b * LSEQ + kq) * QKVP + hh * HDD;
        Ks4[i] = ((const float4*)(rowp + DD))[c4];
        Vs4[i] = ((const float4*)(rowp + 2 * DD))[c4];
    }
    __syncthreads();
    int q = blockIdx.y * 64 + tid;
    if (q >= LSEQ) return;
    const float4* qp = (const float4*)(qkv + (size_t)(b * LSEQ + q) * QKVP + hh * HDD);
    float4 q0 = qp[0], q1 = qp[1], q2 = qp[2], q3 = qp[3], q4 = qp[4];
    const float scale = 0.22360679774997896f;
    float mx = -3.0e38f, sum = 0.f;
    float4 z = {0.f, 0.f, 0.f, 0.f};
    float4 ac0 = z, ac1 = z, ac2 = z, ac3 = z, ac4 = z;
    for (int k = 0; k < LSEQ; ++k) {
        const float4* kp = Ks4 + k * 5;
        float4 K0 = kp[0], K1 = kp[1], K2 = kp[2], K3 = kp[3], K4 = kp[4];
        float a0 = q0.x * K0.x + q0.y * K0.y + q0.z * K0.z + q0.w * K0.w;
        float a1 = q1.x * K1.x + q1.y * K1.y + q1.z * K1.z + q1.w * K1.w;
        float a2 = q2.x * K2.x + q2.y * K2.y + q2.z * K2.z + q2.w * K2.w;
        float a3 = q3.x * K3.x + q3.y * K3.y + q3.z * K3.z + q3.w * K3.w;
        float a4 = q4.x * K4.x + q4.y * K4.y + q4.z * K4.z + q4.w * K4.w;
        float s = (((a0 + a1) + (a2 + a3)) + a4) * scale;
        float mn = fmaxf(mx, s);
        float corr = __expf(mx - mn);
        float p = __expf(s - mn);
        mx = mn;
        sum = sum * corr + p;
        const float4* vp = Vs4 + k * 5;
        float4 V0 = vp[0], V1 = vp[1], V2 = vp[2], V3 = vp[3], V4 = vp[4];
        UPD4(ac0, V0); UPD4(ac1, V1); UPD4(ac2, V2); UPD4(ac3, V3); UPD4(ac4, V4);
    }
    float inv = 1.f / sum;
    float4* op = (float4*)(aout + (size_t)(b * LSEQ + q) * DD + hh * HDD);
    float4 o0 = {ac0.x * inv, ac0.y * inv, ac0.z * inv, ac0.w * inv};
    float4 o1 = {ac1.x * inv, ac1.y * inv, ac1.z * inv, ac1.w * inv};
    float4 o2 = {ac2.x * inv, ac2.y * inv, ac2.z * inv, ac2.w * inv};
    float4 o3 = {ac3.x * inv, ac3.y * inv, ac3.z * inv, ac3.w * inv};
    float4 o4 = {ac4.x * inv, ac4.y * inv, ac4.z * inv, ac4.w * inv};
    op[0] = o0; op[1] = o1; op[2] = o2; op[3] = o3; op[4] = o4;
}

// ================= t = LN(t + delta[.. x ds]) (+ optional final linear) =================
__global__ void k_addln(float* t, const float* delta, int ds,
                        const float* g, const float* b,
                        const float* lw, const float* lb, float* outp) {
    int n = blockIdx.x, lane = threadIdx.x;
    int c0 = lane, c1 = lane + 64, c2 = lane + 128;
    float v0 = t[n * DD + c0] + delta[(size_t)n * ds + c0];
    float v1 = t[n * DD + c1] + delta[(size_t)n * ds + c1];
    float v2 = (lane < 32) ? (t[n * DD + c2] + delta[(size_t)n * ds + c2]) : 0.f;
    float m = wred(v0 + v1 + v2) * (1.f / DD);
    float d0 = v0 - m, d1 = v1 - m, d2 = (lane < 32) ? (v2 - m) : 0.f;
    float var = wred(d0 * d0 + d1 * d1 + d2 * d2) * (1.f / DD);
    float rs = rsqrtf(var + 1e-5f);
    float n0 = d0 * rs * g[c0] + b[c0];
    float n1 = d1 * rs * g[c1] + b[c1];
    float n2 = (lane < 32) ? (d2 * rs * g[c2] + b[c2]) : 0.f;
    t[n * DD + c0] = n0;
    t[n * DD + c1] = n1;
    if (lane < 32) t[n * DD + c2] = n2;
    if (outp) {
        #pragma unroll
        for (int cls = 0; cls < NCLS; ++cls) {
            float part = n0 * lw[c0 * NCLS + cls] + n1 * lw[c1 * NCLS + cls]
                       + ((lane < 32) ? n2 * lw[c2 * NCLS + cls] : 0.f);
            float tot = wred(part);
            if (lane == 0) outp[n * NCLS + cls] = tot + lb[cls];
        }
    }
}

extern "C" void kernel_launch(void* const* d_in, const int* in_sizes, int n_in,
                              void* d_out, int out_size, void* d_ws, size_t ws_size,
                              hipStream_t stream) {
    (void)in_sizes; (void)n_in; (void)out_size; (void)ws_size;
    const float* x      = (const float*)d_in[0];
    const float* eattr  = (const float*)d_in[1];
    const float* cheb_w = (const float*)d_in[2];
    const float* cheb_b = (const float*)d_in[3];
    const float* ee_w   = (const float*)d_in[4];
    const float* ee_b   = (const float*)d_in[5];
    const float* mlp_w1 = (const float*)d_in[6];
    const float* mlp_b1 = (const float*)d_in[7];
    const float* mlp_w2 = (const float*)d_in[8];
    const float* mlp_b2 = (const float*)d_in[9];
    const float* root_w = (const float*)d_in[10];
    const float* conv_b = (const float*)d_in[11];
    const float* ln_g   = (const float*)d_in[12];
    const float* ln_b   = (const float*)d_in[13];
    const float* ain_w  = (const float*)d_in[14];
    const float* ain_b  = (const float*)d_in[15];
    const float* aow    = (const float*)d_in[16];
    const float* aob    = (const float*)d_in[17];
    const float* ffw1   = (const float*)d_in[18];
    const float* ffb1   = (const float*)d_in[19];
    const float* ffw2   = (const float*)d_in[20];
    const float* ffb2   = (const float*)d_in[21];
    const float* t1g    = (const float*)d_in[22];
    const float* t1b    = (const float*)d_in[23];
    const float* t2g    = (const float*)d_in[24];
    const float* t2b    = (const float*)d_in[25];
    const float* lin_w  = (const float*)d_in[26];
    const float* lin_b  = (const float*)d_in[27];
    const int* ei       = (const int*)d_in[29];

    char* w = (char*)d_ws;
    size_t off = 0;
    auto alloc = [&](size_t bytes) -> void* {
        void* p = w + off;
        off += (bytes + 255) & ~(size_t)255;
        return p;
    };
    bf16*  bpack = (bf16*)alloc((size_t)NLAY * NCT * 64 * NH * 2);
    float* t1all = (float*)alloc((size_t)NLAY * NE * H3D * 4);
    float* h     = (float*)alloc((size_t)NND * NH * 4);
    bf16*  hbf   = (bf16*)alloc((size_t)NPAD * NH * 2);
    bf16*  HW    = (bf16*)alloc((size_t)NPAD * NCOLS * 2);
    float* tbuf  = (float*)alloc((size_t)NPAD * DD * 4);
    float* qkvC  = (float*)alloc((size_t)NPAD * QKVP * 4);
    float* abuf  = (float*)alloc((size_t)NPAD * DD * 4);
    float* prjC  = (float*)alloc((size_t)NPAD * PRJP * 4);
    float* f1    = (float*)alloc((size_t)NPAD * FFD * 4);
    int*   deg   = (int*)alloc((size_t)NND * 4);
    int*   csr   = (int*)alloc((size_t)NND * CSTR * 4);
    bf16*  bqkv  = (bf16*)alloc((size_t)TLAY * QKVP * DD * 2);
    bf16*  bproj = (bf16*)alloc((size_t)TLAY * PRJP * DD * 2);
    bf16*  bff1  = (bf16*)alloc((size_t)TLAY * FFD * DD * 2);
    bf16*  bff2  = (bf16*)alloc((size_t)TLAY * PRJP * FFD * 2);
    float* tbias = (float*)alloc((size_t)TLAY * 1152 * 4);

    hipMemsetAsync(deg, 0, (size_t)NND * 4, stream);

    k_setup<<<SB_TOT, 256, 0, stream>>>(x, cheb_w, cheb_b, hbf,
                                        eattr, ee_w, ee_b, mlp_w1, mlp_b1, t1all,
                                        mlp_w2, mlp_b2, root_w, bpack, ei, deg, csr,
                                        ain_w, aow, ffw1, ffw2,
                                        ain_b, aob, ffb1, ffb2,
                                        bqkv, bproj, bff1, bff2, tbias);

    // --- 10 NNConv layers ---
    for (int l = 0; l < NLAY; ++l) {
        k_gemm<<<dim3(NCT, 14), 256, 0, stream>>>(hbf, bpack + (size_t)l * NCT * 64 * NH, HW);
        k_edgeg<<<NND, 128, 0, stream>>>(ei, t1all + (size_t)l * NE * H3D, HW, h, hbf, tbuf,
                                         ln_g, ln_b, conv_b, deg, csr, l);
    }

    // --- transformer encoder: MFMA GEMMs + attn + addln ---
    for (int tl = 0; tl < TLAY; ++tl) {
        const float* bb = tbias + (size_t)tl * 1152;
        k_gmm<<<dim3(QKVP / 64, 14), 256, 0, stream>>>(tbuf, bqkv + (size_t)tl * QKVP * DD,
                                                       bb, qkvC, 5, DD, QKVP, 0);
        k_attn<<<dim3(BSZ * THD, 2), 64, 0, stream>>>(qkvC, abuf);
        k_gmm<<<dim3(PRJP / 64, 14), 256, 0, stream>>>(abuf, bproj + (size_t)tl * PRJP * DD,
                                                       bb + 512, prjC, 5, DD, PRJP, 0);
        k_addln<<<NND, 64, 0, stream>>>(tbuf, prjC, PRJP, t1g + (size_t)tl * DD,
                                        t1b + (size_t)tl * DD, nullptr, nullptr, nullptr);
        k_gmm<<<dim3(FFD / 64, 14), 256, 0, stream>>>(tbuf, bff1 + (size_t)tl * FFD * DD,
                                                      bb + 704, f1, 5, DD, FFD, 1);
        k_gmm<<<dim3(PRJP / 64, 14), 256, 0, stream>>>(f1, bff2 + (size_t)tl * PRJP * FFD,
                                                       bb + 960, prjC, 8, FFD, PRJP, 0);
        int last = (tl == TLAY - 1);
        k_addln<<<NND, 64, 0, stream>>>(tbuf, prjC, PRJP, t2g + (size_t)tl * DD,
                                        t2b + (size_t)tl * DD,
                                        last ? lin_w : nullptr, last ? lin_b : nullptr,
                                        last ? (float*)d_out : nullptr);
    }
}